// Round 1
// 208.441 us; speedup vs baseline: 1.0158x; 1.0158x over previous
//
#include <hip/hip_runtime.h>

// WaveNet inference on MFMA. Exploits: (1) only last timestep feeds the FC
// head, (2) skip overwritten each layer (only layer 15's matters),
// (3) receptive field at t=T-1 is 77 steps.
// Round 14 = R13 + latency-chain diet:
//  - weight prefetch+commit moved OFF the compute waves for T<=2 layers
//    (waves wv>=T are idle in the phases; they now do all staging: loads
//    issued at layer top, convert+write in the phase2/3 window)
//  - T==1 layers (10-15) drop the mid __syncthreads (handoff is wave-0
//    local; lgkmcnt suffices, same as the existing phase2->3 handoff)
//  - fused activation tanh(x)*sigmoid(y) = (1-u)*rcp((1+u)(1+v)),
//    u=e^-2x, v=e^-y -- kills two full-precision f32 divide sequences
//  - init conv parallel across waves 0..2 (was a 3-tile loop on wave 0)
//  - tail vecA/vecB reads as aligned float4 (was scalar ds_read_b32)
// Regime rules learned (R3/4: >256 thr spills; R8: never trade CUs for
// waves; R9/R11: no serial work to kill barriers; R12: reg plumbing ~ LDS).

#define BB 16
#define TT 8192
#define LL 16
#define W0 77
#define NT 256

typedef __attribute__((ext_vector_type(8)))  short short8;
typedef __attribute__((ext_vector_type(16))) float float16;

#define MFMA_B16(a, b, c) __builtin_amdgcn_mfma_f32_32x32x16_bf16(a, b, c, 0, 0, 0)

__device__ __forceinline__ short f2bs(float f) {   // f32 -> bf16 bits, RNE
  union { float ff; unsigned u; } v; v.ff = f;
  unsigned u = v.u;
  return (short)((u + 0x7FFFu + ((u >> 16) & 1u)) >> 16);
}
__device__ __forceinline__ float b2f(short h) {
  union { unsigned u; float f; } v;
  v.u = ((unsigned)(unsigned short)h) << 16; return v.f;
}

// A-fragment halves from [row][32] bf16 LDS: A[m][k], k-local=(lane>>5)*8+j.
__device__ __forceinline__ void afrag2(const short* src, int row, int kh, short8* out) {
  out[0] = *(const short8*)&src[row * 32 + 8 * kh];
  out[1] = *(const short8*)&src[row * 32 + 16 + 8 * kh];
}

// chunk cid in [0,896): mat=cid>>7, h=(cid>>6)&1, ln=cid&63 -> n=ln&31,k2=ln>>5
// value j: W[16h+8k2+j][n] of matrix mat; dst offset = cid*8 shorts (b128).
__device__ __forceinline__ void load_chunk(
    int li, int cid, float* pf,
    const float* dil_w, const float* filt_w, const float* gate_w, const float* res_w)
{
  int mat = cid >> 7;
  int h = (cid >> 6) & 1, ln = cid & 63;
  int n = ln & 31, k2 = ln >> 5;
  int base = (li * 32 + n) * 32 + 16 * h + 8 * k2;
  if (mat == 6) {
    const float* p = res_w + base;
    #pragma unroll
    for (int j = 0; j < 8; j++) pf[j] = p[j];
  } else {
    const float* w = (mat < 2) ? dil_w : (mat < 4) ? filt_w : gate_w;
    const float* p = w + base * 2 + (mat & 1);
    #pragma unroll
    for (int j = 0; j < 8; j++) pf[j] = p[2 * j];
  }
}

__global__ __launch_bounds__(NT, 1) void wavenet_kernel(
    const int* __restrict__ tokens,
    const float* __restrict__ emb,
    const float* __restrict__ init_w, const float* __restrict__ init_b,
    const float* __restrict__ dil_w,  const float* __restrict__ dil_b,
    const float* __restrict__ filt_w, const float* __restrict__ filt_b,
    const float* __restrict__ gate_w, const float* __restrict__ gate_b,
    const float* __restrict__ res_w,  const float* __restrict__ res_b,
    const float* __restrict__ skip_w, const float* __restrict__ skip_b,
    const float* __restrict__ end1_w, const float* __restrict__ end1_b,
    const float* __restrict__ end2_w, const float* __restrict__ end2_b,
    const float* __restrict__ fc1_w,  const float* __restrict__ fc1_b,
    const float* __restrict__ fc2_w,  const float* __restrict__ fc2_b,
    const float* __restrict__ fc3_w,  const float* __restrict__ fc3_b,
    const float* __restrict__ fc4_w,  const float* __restrict__ fc4_b,
    float* __restrict__ out)
{
  __shared__ __align__(16) short bfw[2][7168];   // weight frags, double buffer
  __shared__ float bias2[2][128];
  __shared__ __align__(16) short xbuf[W0 * 32];
  __shared__ __align__(16) short pool[8624];     // emb stage (init) / rb+xm
  __shared__ int tok[W0];
  __shared__ __align__(16) float vecA[256], vecB[256];

  short* rb = pool;          // 76*32
  short* xm = pool + 2432;   // 76*32

  const int tid  = threadIdx.x;
  const int lane = tid & 63;
  const int wv   = tid >> 6;
  const int m    = lane & 31;
  const int kh   = lane >> 5;
  const int b    = blockIdx.x;

  // ---- tokens ----
  if (tid < W0) tok[tid] = tokens[b * TT + (TT - 1 - tid)];
  __syncthreads();

  // ---- stage emb rows (bf16, rows zero-padded to K=112) ----
  for (int cid = tid; cid < 77 * 14; cid += NT) {
    int u = cid / 14, s = cid % 14;
    const float* er = emb + tok[u] * 100 + s * 8;
    short8 v;
    if (s < 12) {
      #pragma unroll
      for (int j = 0; j < 8; j++) v[j] = f2bs(er[j]);
    } else if (s == 12) {
      #pragma unroll
      for (int j = 0; j < 4; j++) v[j] = f2bs(er[j]);
      #pragma unroll
      for (int j = 4; j < 8; j++) v[j] = 0;
    } else {
      #pragma unroll
      for (int j = 0; j < 8; j++) v[j] = 0;
    }
    *(short8*)&pool[u * 112 + s * 8] = v;
  }
  // stage layer-0 weight frags + biases directly (all threads)
  for (int cid = tid; cid < 896; cid += NT) {
    float pf[8];
    load_chunk(0, cid, pf, dil_w, filt_w, gate_w, res_w);
    short8 v;
    #pragma unroll
    for (int j = 0; j < 8; j++) v[j] = f2bs(pf[j]);
    *(short8*)&bfw[0][cid * 8] = v;
  }
  if (tid < 128) {
    const float* bsrc = (tid < 32) ? dil_b : (tid < 64) ? filt_b : (tid < 96) ? gate_b : res_b;
    bias2[0][tid] = bsrc[tid & 31];
  }
  __syncthreads();

  // ---- init conv (waves 0..2, one 32-row tile each, MFMA over K=112) ----
  if (wv < 3) {
    short8 bi[7];
    #pragma unroll
    for (int s = 0; s < 7; s++) {
      const float* p = init_w + m * 100 + s * 16 + kh * 8;
      short8 v;
      if (s < 6) {
        #pragma unroll
        for (int j = 0; j < 8; j++) v[j] = f2bs(p[j]);
      } else if (kh == 0) {
        #pragma unroll
        for (int j = 0; j < 4; j++) v[j] = f2bs(p[j]);
        #pragma unroll
        for (int j = 4; j < 8; j++) v[j] = 0;
      } else {
        #pragma unroll
        for (int j = 0; j < 8; j++) v[j] = 0;
      }
      bi[s] = v;
    }
    const float binit = init_b[m];
    const int R = wv * 32;
    int u = R + m; if (u > 76) u = 76;
    float16 acc;
    #pragma unroll
    for (int r = 0; r < 16; r++) acc[r] = binit;
    #pragma unroll
    for (int s = 0; s < 7; s++) {
      short8 a = *(const short8*)&pool[u * 112 + s * 16 + kh * 8];
      acc = MFMA_B16(a, bi[s], acc);
    }
    #pragma unroll
    for (int r = 0; r < 16; r++) {
      int row = (r & 3) + 8 * (r >> 2) + 4 * kh;
      int uu = R + row;
      if (uu < W0) xbuf[uu * 32 + m] = f2bs(acc[r]);
    }
  }
  __syncthreads();

  // ---- 16 layers; tiles parallel across waves; staging on idle waves ----
  int Win = W0;
  for (int i = 0; i < LL; i++) {
    const int d = 1 << (i & 3);
    const int Wout = Win - d - 1;
    const int T = (Wout + 32) >> 5;        // tile count, both phases
    const short* bw = bfw[i & 1];
    const float* bs = bias2[i & 1];

    // -- prefetch scheme A (layers 0-2, T==3): all threads, regs, commit
    //    at bottom (only wave 3 is idle; 14 chunks on 64 threads doesn't fit)
    float pfo[4][8];
    float pbias = 0.f;
    const int nch = (tid < 128) ? 4 : 3;   // 896 = 3*256 + 128
    const bool oldpf = (T >= 3) && (i + 1 < LL);
    if (oldpf) {
      #pragma unroll
      for (int q = 0; q < 4; q++) {
        if (q < nch)
          load_chunk(i + 1, tid + q * NT, pfo[q], dil_w, filt_w, gate_w, res_w);
      }
      if (tid < 128) {
        const float* bsrc = (tid < 32) ? dil_b : (tid < 64) ? filt_b : (tid < 96) ? gate_b : res_b;
        pbias = bsrc[(i + 1) * 32 + (tid & 31)];
      }
    }
    // -- prefetch scheme B (T<=2): waves wv>=T carry the whole staging.
    //    Loads issued here (<=56 in flight, under vmcnt cap); converts and
    //    LDS writes land in the phase2/3 window. Compute waves do nothing.
    const bool newpf = (T <= 2) && (i + 1 < LL) && (wv >= T);
    const int nP = NT - T * 64;            // 128 (T==2) or 192 (T==1)
    const int ptid = tid - T * 64;
    float pfn[7][8];
    if (newpf) {
      #pragma unroll
      for (int q = 0; q < 7; q++) {
        int c = ptid + q * nP;
        if (c < 896) load_chunk(i + 1, c, pfn[q], dil_w, filt_w, gate_w, res_w);
      }
    }

    // phase1: residual[vr] = db + D0@x[vr+d] + D1@x[vr], rows [0,Wout]
    // + hoisted phase2/3 B-frag loads (weight buffer stable from layer top;
    //   latency hides under phase1's MFMA chain, lives across mid barrier)
    short8 BW[5][2];
    if (wv < T) {
      const int R = wv * 32;
      short8 B0[2], B1[2];
      #pragma unroll
      for (int h = 0; h < 2; h++) {
        B0[h] = *(const short8*)&bw[((0 * 2 + h) * 64 + lane) * 8];
        B1[h] = *(const short8*)&bw[((1 * 2 + h) * 64 + lane) * 8];
      }
      #pragma unroll
      for (int mt = 0; mt < 5; mt++)
        #pragma unroll
        for (int h = 0; h < 2; h++)
          BW[mt][h] = *(const short8*)&bw[(((mt + 2) * 2 + h) * 64 + lane) * 8];
      int vra = R + m + d; if (vra > Win - 1) vra = Win - 1;
      int vrz = R + m;     if (vrz > Win - 1) vrz = Win - 1;
      short8 aA[2], aZ[2];
      afrag2(xbuf, vra, kh, aA);
      afrag2(xbuf, vrz, kh, aZ);
      float16 acc;
      const float bc = bs[m];
      #pragma unroll
      for (int r = 0; r < 16; r++) acc[r] = bc;
      acc = MFMA_B16(aA[0], B0[0], acc);
      acc = MFMA_B16(aA[1], B0[1], acc);
      acc = MFMA_B16(aZ[0], B1[0], acc);
      acc = MFMA_B16(aZ[1], B1[1], acc);
      #pragma unroll
      for (int r = 0; r < 16; r++) {
        int row = (r & 3) + 8 * (r >> 2) + 4 * kh;
        int vr = R + row;
        if (vr <= Wout) rb[vr * 32 + m] = f2bs(acc[r]);
      }
    }
    if (T >= 2) {
      __syncthreads();                      // cross-wave rb handoff
    } else {
      asm volatile("s_waitcnt lgkmcnt(0)" ::: "memory");  // wave-0 local
    }

    // phase2+3 (same wave & tile; wave-local xm handoff via lgkmcnt)
    if (wv < T) {
      const int R = wv * 32;
      int r1 = R + m + 1; if (r1 > Wout) r1 = Wout;
      int r0 = R + m;     if (r0 > Wout) r0 = Wout;
      short8 a1[2], a0[2];
      afrag2(rb, r1, kh, a1);
      afrag2(rb, r0, kh, a0);
      float16 accF, accG;
      const float bf = bs[32 + m], bg = bs[64 + m];
      #pragma unroll
      for (int r = 0; r < 16; r++) { accF[r] = bf; accG[r] = bg; }
      accF = MFMA_B16(a1[0], BW[0][0], accF);
      accF = MFMA_B16(a1[1], BW[0][1], accF);
      accF = MFMA_B16(a0[0], BW[1][0], accF);
      accF = MFMA_B16(a0[1], BW[1][1], accF);
      accG = MFMA_B16(a1[0], BW[2][0], accG);
      accG = MFMA_B16(a1[1], BW[2][1], accG);
      accG = MFMA_B16(a0[0], BW[3][0], accG);
      accG = MFMA_B16(a0[1], BW[3][1], accG);
      #pragma unroll
      for (int r = 0; r < 16; r++) {
        int row = (r & 3) + 8 * (r >> 2) + 4 * kh;
        int uf = R + row;
        if (uf < Wout) {
          // tanh(x)*sigmoid(y) = (1-u) / ((1+u)(1+v)), u=e^-2x, v=e^-y
          float u = __expf(-2.f * accF[r]);
          float v = __expf(-accG[r]);
          float fg = (1.f - u) * __builtin_amdgcn_rcpf((1.f + u) * (1.f + v));
          xm[uf * 32 + m] = f2bs(fg);
        }
      }
      asm volatile("s_waitcnt lgkmcnt(0)" ::: "memory");

      // phase3: xnext = rbias + R@xmid + residual[row+1] (bf16 carry in C)
      int rx = R + m; if (rx > Wout - 1) rx = Wout - 1;
      short8 aX[2];
      afrag2(xm, rx, kh, aX);
      float16 accX;
      const float br = bs[96 + m];
      #pragma unroll
      for (int r = 0; r < 16; r++) {
        int row = (r & 3) + 8 * (r >> 2) + 4 * kh;
        int rr = R + row + 1; if (rr > Wout) rr = Wout;
        accX[r] = br + b2f(rb[rr * 32 + m]);
      }
      accX = MFMA_B16(aX[0], BW[4][0], accX);
      accX = MFMA_B16(aX[1], BW[4][1], accX);
      #pragma unroll
      for (int r = 0; r < 16; r++) {
        int row = (r & 3) + 8 * (r >> 2) + 4 * kh;
        int uf = R + row;
        if (uf < Wout) xbuf[uf * 32 + m] = f2bs(accX[r]);
      }
    } else if (newpf) {
      // staging waves: convert + write layer i+1 frags into the flip buffer
      short* dst = bfw[(i + 1) & 1];
      #pragma unroll
      for (int q = 0; q < 7; q++) {
        int c = ptid + q * nP;
        if (c < 896) {
          short8 v;
          #pragma unroll
          for (int j = 0; j < 8; j++) v[j] = f2bs(pfn[q][j]);
          *(short8*)&dst[c * 8] = v;
        }
      }
      for (int t2 = ptid; t2 < 128; t2 += nP) {
        const float* bsrc = (t2 < 32) ? dil_b : (t2 < 64) ? filt_b : (t2 < 96) ? gate_b : res_b;
        bias2[(i + 1) & 1][t2] = bsrc[(i + 1) * 32 + (t2 & 31)];
      }
    }

    // commit scheme-A frags (layers 0-2 only; conflict-free b128 writes)
    if (oldpf) {
      short* dst = bfw[(i + 1) & 1];
      #pragma unroll
      for (int q = 0; q < 4; q++) {
        if (q < nch) {
          short8 v;
          #pragma unroll
          for (int j = 0; j < 8; j++) v[j] = f2bs(pfo[q][j]);
          *(short8*)&dst[(tid + q * NT) * 8] = v;
        }
      }
      if (tid < 128) bias2[(i + 1) & 1][tid] = pbias;
    }
    __syncthreads();
    Win = Wout;
  }

  // ---- tail (f32 VALU, 4 waves): skip(l15) -> end1 -> end2 -> fc1..fc4 ----
  {
    float acc = skip_b[15 * 256 + tid];
    const float* wr = skip_w + (15 * 256 + tid) * 32;
    #pragma unroll
    for (int k = 0; k < 32; k += 4) {
      float4 w = *(const float4*)&wr[k];
      acc += (w.x * b2f(xm[k]) + w.y * b2f(xm[k+1])) + (w.z * b2f(xm[k+2]) + w.w * b2f(xm[k+3]));
    }
    vecA[tid] = fmaxf(acc, 0.f);
  }
  __syncthreads();
  {
    const float* wr = end1_w + tid * 256;
    float a4[4] = {0.f, 0.f, 0.f, 0.f};
    #pragma unroll 4
    for (int k = 0; k < 256; k += 16) {
      #pragma unroll
      for (int q = 0; q < 4; q++) {
        float4 w = *(const float4*)&wr[k + 4 * q];
        float4 a = *(const float4*)&vecA[k + 4 * q];
        a4[q] += (w.x * a.x + w.y * a.y) + (w.z * a.z + w.w * a.w);
      }
    }
    vecB[tid] = fmaxf(end1_b[tid] + (a4[0] + a4[1]) + (a4[2] + a4[3]), 0.f);
  }
  __syncthreads();
  float h2;
  {
    const float* wr = end2_w + tid * 256;
    float a4[4] = {0.f, 0.f, 0.f, 0.f};
    #pragma unroll 4
    for (int k = 0; k < 256; k += 16) {
      #pragma unroll
      for (int q = 0; q < 4; q++) {
        float4 w = *(const float4*)&wr[k + 4 * q];
        float4 a = *(const float4*)&vecB[k + 4 * q];
        a4[q] += (w.x * a.x + w.y * a.y) + (w.z * a.z + w.w * a.w);
      }
    }
    h2 = end2_b[tid] + (a4[0] + a4[1]) + (a4[2] + a4[3]);
  }
  __syncthreads();
  vecA[tid] = h2;
  __syncthreads();
  if (tid < 128) {
    const float* wr = fc1_w + tid * 256;
    float a4[4] = {0.f, 0.f, 0.f, 0.f};
    #pragma unroll 4
    for (int k = 0; k < 256; k += 16) {
      #pragma unroll
      for (int q = 0; q < 4; q++) {
        float4 w = *(const float4*)&wr[k + 4 * q];
        float4 a = *(const float4*)&vecA[k + 4 * q];
        a4[q] += (w.x * a.x + w.y * a.y) + (w.z * a.z + w.w * a.w);
      }
    }
    vecB[tid] = fmaxf(fc1_b[tid] + (a4[0] + a4[1]) + (a4[2] + a4[3]), 0.f);
  }
  __syncthreads();
  if (tid < 128) {
    const float* wr = fc2_w + tid * 128;
    float a4[4] = {0.f, 0.f, 0.f, 0.f};
    #pragma unroll 2
    for (int k = 0; k < 128; k += 16) {
      #pragma unroll
      for (int q = 0; q < 4; q++) {
        float4 w = *(const float4*)&wr[k + 4 * q];
        float4 a = *(const float4*)&vecB[k + 4 * q];
        a4[q] += (w.x * a.x + w.y * a.y) + (w.z * a.z + w.w * a.w);
      }
    }
    vecA[tid] = fmaxf(fc2_b[tid] + (a4[0] + a4[1]) + (a4[2] + a4[3]), 0.f);
  }
  __syncthreads();
  if (tid < 64) {
    const float* wr = fc3_w + tid * 128;
    float a4[4] = {0.f, 0.f, 0.f, 0.f};
    #pragma unroll 2
    for (int k = 0; k < 128; k += 16) {
      #pragma unroll
      for (int q = 0; q < 4; q++) {
        float4 w = *(const float4*)&wr[k + 4 * q];
        float4 a = *(const float4*)&vecA[k + 4 * q];
        a4[q] += (w.x * a.x + w.y * a.y) + (w.z * a.z + w.w * a.w);
      }
    }
    vecB[tid] = fmaxf(fc3_b[tid] + (a4[0] + a4[1]) + (a4[2] + a4[3]), 0.f);
  }
  __syncthreads();
  {
    const float* wr = fc4_w + tid * 64;
    float a4[4] = {0.f, 0.f, 0.f, 0.f};
    #pragma unroll
    for (int k = 0; k < 64; k += 16) {
      #pragma unroll
      for (int q = 0; q < 4; q++) {
        float4 w = *(const float4*)&wr[k + 4 * q];
        float4 a = *(const float4*)&vecB[k + 4 * q];
        a4[q] += (w.x * a.x + w.y * a.y) + (w.z * a.z + w.w * a.w);
      }
    }
    out[b * 256 + tid] = fc4_b[tid] + (a4[0] + a4[1]) + (a4[2] + a4[3]);
  }
}

extern "C" void kernel_launch(void* const* d_in, const int* in_sizes, int n_in,
                              void* d_out, int out_size, void* d_ws, size_t ws_size,
                              hipStream_t stream) {
  wavenet_kernel<<<BB, NT, 0, stream>>>(
      (const int*)d_in[0],    (const float*)d_in[1],  (const float*)d_in[2],  (const float*)d_in[3],
      (const float*)d_in[4],  (const float*)d_in[5],  (const float*)d_in[6],  (const float*)d_in[7],
      (const float*)d_in[8],  (const float*)d_in[9],  (const float*)d_in[10], (const float*)d_in[11],
      (const float*)d_in[12], (const float*)d_in[13], (const float*)d_in[14], (const float*)d_in[15],
      (const float*)d_in[16], (const float*)d_in[17], (const float*)d_in[18], (const float*)d_in[19],
      (const float*)d_in[20], (const float*)d_in[21], (const float*)d_in[22], (const float*)d_in[23],
      (const float*)d_in[24], (const float*)d_in[25], (float*)d_out);
}

// Round 2
// 204.976 us; speedup vs baseline: 1.0330x; 1.0169x over previous
//
#include <hip/hip_runtime.h>

// WaveNet inference on MFMA. Exploits: (1) only last timestep feeds the FC
// head, (2) skip overwritten each layer (only layer 15's matters),
// (3) receptive field at t=T-1 is 77 steps.
// Round 15 = R14 + in-register pipeline for layers 11..15 (windows <= 32
// rows fit one wave's lanes). Operand-swapped MFMA: D' = W^T . X^T keeps
// activations in [chan->regs][time->lanes] layout across ALL phases; the
// inter-phase handoff is cvt_pk_bf16 + __shfl half-exchange (T12 pattern)
// instead of LDS write->drain->read round trips. Dilated taps = clamped
// lane shifts. Weight frags staged in bfw are bit-identical as A-frags of
// W^T (same LDS indices). Layer 15 phase3 dropped (dead); lanes 0/32 spill
// gated row 0 to xm for the tail.
// Regime rules learned (R3/4: >256 thr spills; R8: never trade CUs for
// waves; R9/R11: no serial work to kill barriers; R12: reg plumbing ~ LDS;
// R14: staging issue off compute waves ~neutral -> LDS hops are the chain).

#define BB 16
#define TT 8192
#define LL 16
#define W0 77
#define NT 256

typedef __attribute__((ext_vector_type(8)))  short short8;
typedef __attribute__((ext_vector_type(16))) float float16;

#define MFMA_B16(a, b, c) __builtin_amdgcn_mfma_f32_32x32x16_bf16(a, b, c, 0, 0, 0)

__device__ __forceinline__ short f2bs(float f) {   // f32 -> bf16 bits, RNE
  union { float ff; unsigned u; } v; v.ff = f;
  unsigned u = v.u;
  return (short)((u + 0x7FFFu + ((u >> 16) & 1u)) >> 16);
}
__device__ __forceinline__ float b2f(short h) {
  union { unsigned u; float f; } v;
  v.u = ((unsigned)(unsigned short)h) << 16; return v.f;
}
__device__ __forceinline__ unsigned cvtpk(float lo, float hi) {
  unsigned r;
  asm("v_cvt_pk_bf16_f32 %0, %1, %2" : "=v"(r) : "v"(lo), "v"(hi));
  return r;
}
__device__ __forceinline__ short8 mk8(unsigned a, unsigned b, unsigned c, unsigned d) {
  union { unsigned u[4]; short8 s; } z;
  z.u[0] = a; z.u[1] = b; z.u[2] = c; z.u[3] = d; return z.s;
}
__device__ __forceinline__ float u2f(unsigned u) {
  union { unsigned x; float f; } z; z.x = u; return z.f;
}
// Assemble next-phase B-frag words from own packed D'-words + cross-half
// words (from lane^32). own[q]=pack(acc[2q],acc[2q+1]) holds c=(2q&3)+8*(q>>1)+4kh.
__device__ __forceinline__ void asmb(const unsigned* own, const unsigned* cr,
                                     int kh, unsigned* o) {
  #pragma unroll
  for (int h = 0; h < 2; h++) {
    o[4*h+0] = kh ? cr[4*h+2] : own[4*h+0];
    o[4*h+1] = kh ? cr[4*h+3] : own[4*h+1];
    o[4*h+2] = kh ? own[4*h+2] : cr[4*h+0];
    o[4*h+3] = kh ? own[4*h+3] : cr[4*h+1];
  }
}

// A-fragment halves from [row][32] bf16 LDS: A[m][k], k-local=(lane>>5)*8+j.
__device__ __forceinline__ void afrag2(const short* src, int row, int kh, short8* out) {
  out[0] = *(const short8*)&src[row * 32 + 8 * kh];
  out[1] = *(const short8*)&src[row * 32 + 16 + 8 * kh];
}

// chunk cid in [0,896): mat=cid>>7, h=(cid>>6)&1, ln=cid&63 -> n=ln&31,k2=ln>>5
// value j: W[16h+8k2+j][n] of matrix mat; dst offset = cid*8 shorts (b128).
__device__ __forceinline__ void load_chunk(
    int li, int cid, float* pf,
    const float* dil_w, const float* filt_w, const float* gate_w, const float* res_w)
{
  int mat = cid >> 7;
  int h = (cid >> 6) & 1, ln = cid & 63;
  int n = ln & 31, k2 = ln >> 5;
  int base = (li * 32 + n) * 32 + 16 * h + 8 * k2;
  if (mat == 6) {
    const float* p = res_w + base;
    #pragma unroll
    for (int j = 0; j < 8; j++) pf[j] = p[j];
  } else {
    const float* w = (mat < 2) ? dil_w : (mat < 4) ? filt_w : gate_w;
    const float* p = w + base * 2 + (mat & 1);
    #pragma unroll
    for (int j = 0; j < 8; j++) pf[j] = p[2 * j];
  }
}

__global__ __launch_bounds__(NT, 1) void wavenet_kernel(
    const int* __restrict__ tokens,
    const float* __restrict__ emb,
    const float* __restrict__ init_w, const float* __restrict__ init_b,
    const float* __restrict__ dil_w,  const float* __restrict__ dil_b,
    const float* __restrict__ filt_w, const float* __restrict__ filt_b,
    const float* __restrict__ gate_w, const float* __restrict__ gate_b,
    const float* __restrict__ res_w,  const float* __restrict__ res_b,
    const float* __restrict__ skip_w, const float* __restrict__ skip_b,
    const float* __restrict__ end1_w, const float* __restrict__ end1_b,
    const float* __restrict__ end2_w, const float* __restrict__ end2_b,
    const float* __restrict__ fc1_w,  const float* __restrict__ fc1_b,
    const float* __restrict__ fc2_w,  const float* __restrict__ fc2_b,
    const float* __restrict__ fc3_w,  const float* __restrict__ fc3_b,
    const float* __restrict__ fc4_w,  const float* __restrict__ fc4_b,
    float* __restrict__ out)
{
  __shared__ __align__(16) short bfw[2][7168];   // weight frags, double buffer
  __shared__ __align__(16) float bias2[2][128];
  __shared__ __align__(16) short xbuf[W0 * 32];
  __shared__ __align__(16) short pool[8624];     // emb stage (init) / rb+xm
  __shared__ int tok[W0];
  __shared__ __align__(16) float vecA[256], vecB[256];

  short* rb = pool;          // 76*32
  short* xm = pool + 2432;   // 76*32

  const int tid  = threadIdx.x;
  const int lane = tid & 63;
  const int wv   = tid >> 6;
  const int m    = lane & 31;
  const int kh   = lane >> 5;
  const int b    = blockIdx.x;

  // ---- tokens ----
  if (tid < W0) tok[tid] = tokens[b * TT + (TT - 1 - tid)];
  __syncthreads();

  // ---- stage emb rows (bf16, rows zero-padded to K=112) ----
  for (int cid = tid; cid < 77 * 14; cid += NT) {
    int u = cid / 14, s = cid % 14;
    const float* er = emb + tok[u] * 100 + s * 8;
    short8 v;
    if (s < 12) {
      #pragma unroll
      for (int j = 0; j < 8; j++) v[j] = f2bs(er[j]);
    } else if (s == 12) {
      #pragma unroll
      for (int j = 0; j < 4; j++) v[j] = f2bs(er[j]);
      #pragma unroll
      for (int j = 4; j < 8; j++) v[j] = 0;
    } else {
      #pragma unroll
      for (int j = 0; j < 8; j++) v[j] = 0;
    }
    *(short8*)&pool[u * 112 + s * 8] = v;
  }
  // stage layer-0 weight frags + biases directly (all threads)
  for (int cid = tid; cid < 896; cid += NT) {
    float pf[8];
    load_chunk(0, cid, pf, dil_w, filt_w, gate_w, res_w);
    short8 v;
    #pragma unroll
    for (int j = 0; j < 8; j++) v[j] = f2bs(pf[j]);
    *(short8*)&bfw[0][cid * 8] = v;
  }
  if (tid < 128) {
    const float* bsrc = (tid < 32) ? dil_b : (tid < 64) ? filt_b : (tid < 96) ? gate_b : res_b;
    bias2[0][tid] = bsrc[tid & 31];
  }
  __syncthreads();

  // ---- init conv (waves 0..2, one 32-row tile each, MFMA over K=112) ----
  if (wv < 3) {
    short8 bi[7];
    #pragma unroll
    for (int s = 0; s < 7; s++) {
      const float* p = init_w + m * 100 + s * 16 + kh * 8;
      short8 v;
      if (s < 6) {
        #pragma unroll
        for (int j = 0; j < 8; j++) v[j] = f2bs(p[j]);
      } else if (kh == 0) {
        #pragma unroll
        for (int j = 0; j < 4; j++) v[j] = f2bs(p[j]);
        #pragma unroll
        for (int j = 4; j < 8; j++) v[j] = 0;
      } else {
        #pragma unroll
        for (int j = 0; j < 8; j++) v[j] = 0;
      }
      bi[s] = v;
    }
    const float binit = init_b[m];
    const int R = wv * 32;
    int u = R + m; if (u > 76) u = 76;
    float16 acc;
    #pragma unroll
    for (int r = 0; r < 16; r++) acc[r] = binit;
    #pragma unroll
    for (int s = 0; s < 7; s++) {
      short8 a = *(const short8*)&pool[u * 112 + s * 16 + kh * 8];
      acc = MFMA_B16(a, bi[s], acc);
    }
    #pragma unroll
    for (int r = 0; r < 16; r++) {
      int row = (r & 3) + 8 * (r >> 2) + 4 * kh;
      int uu = R + row;
      if (uu < W0) xbuf[uu * 32 + m] = f2bs(acc[r]);
    }
  }
  __syncthreads();

  // ---- layers 0..10 (LDS pipeline; windows > 32 rows) ----
  int Win = W0;
  for (int i = 0; i < 11; i++) {
    const int d = 1 << (i & 3);
    const int Wout = Win - d - 1;
    const int T = (Wout + 32) >> 5;        // tile count, both phases
    const short* bw = bfw[i & 1];
    const float* bs = bias2[i & 1];

    // -- prefetch scheme A (layers 0-2, T==3): all threads, regs, commit
    float pfo[4][8];
    float pbias = 0.f;
    const int nch = (tid < 128) ? 4 : 3;   // 896 = 3*256 + 128
    const bool oldpf = (T >= 3) && (i + 1 < LL);
    if (oldpf) {
      #pragma unroll
      for (int q = 0; q < 4; q++) {
        if (q < nch)
          load_chunk(i + 1, tid + q * NT, pfo[q], dil_w, filt_w, gate_w, res_w);
      }
      if (tid < 128) {
        const float* bsrc = (tid < 32) ? dil_b : (tid < 64) ? filt_b : (tid < 96) ? gate_b : res_b;
        pbias = bsrc[(i + 1) * 32 + (tid & 31)];
      }
    }
    // -- prefetch scheme B (T<=2): waves wv>=T carry the whole staging.
    const bool newpf = (T <= 2) && (i + 1 < LL) && (wv >= T);
    const int nP = NT - T * 64;            // 128 (T==2) or 192 (T==1)
    const int ptid = tid - T * 64;
    float pfn[7][8];
    if (newpf) {
      #pragma unroll
      for (int q = 0; q < 7; q++) {
        int c = ptid + q * nP;
        if (c < 896) load_chunk(i + 1, c, pfn[q], dil_w, filt_w, gate_w, res_w);
      }
    }

    // phase1: residual[vr] = db + D0@x[vr+d] + D1@x[vr], rows [0,Wout]
    short8 BW[5][2];
    if (wv < T) {
      const int R = wv * 32;
      short8 B0[2], B1[2];
      #pragma unroll
      for (int h = 0; h < 2; h++) {
        B0[h] = *(const short8*)&bw[((0 * 2 + h) * 64 + lane) * 8];
        B1[h] = *(const short8*)&bw[((1 * 2 + h) * 64 + lane) * 8];
      }
      #pragma unroll
      for (int mt = 0; mt < 5; mt++)
        #pragma unroll
        for (int h = 0; h < 2; h++)
          BW[mt][h] = *(const short8*)&bw[(((mt + 2) * 2 + h) * 64 + lane) * 8];
      int vra = R + m + d; if (vra > Win - 1) vra = Win - 1;
      int vrz = R + m;     if (vrz > Win - 1) vrz = Win - 1;
      short8 aA[2], aZ[2];
      afrag2(xbuf, vra, kh, aA);
      afrag2(xbuf, vrz, kh, aZ);
      float16 acc;
      const float bc = bs[m];
      #pragma unroll
      for (int r = 0; r < 16; r++) acc[r] = bc;
      acc = MFMA_B16(aA[0], B0[0], acc);
      acc = MFMA_B16(aA[1], B0[1], acc);
      acc = MFMA_B16(aZ[0], B1[0], acc);
      acc = MFMA_B16(aZ[1], B1[1], acc);
      #pragma unroll
      for (int r = 0; r < 16; r++) {
        int row = (r & 3) + 8 * (r >> 2) + 4 * kh;
        int vr = R + row;
        if (vr <= Wout) rb[vr * 32 + m] = f2bs(acc[r]);
      }
    }
    if (T >= 2) {
      __syncthreads();                      // cross-wave rb handoff
    } else {
      asm volatile("s_waitcnt lgkmcnt(0)" ::: "memory");  // wave-0 local
    }

    // phase2+3 (same wave & tile; wave-local xm handoff via lgkmcnt)
    if (wv < T) {
      const int R = wv * 32;
      int r1 = R + m + 1; if (r1 > Wout) r1 = Wout;
      int r0 = R + m;     if (r0 > Wout) r0 = Wout;
      short8 a1[2], a0[2];
      afrag2(rb, r1, kh, a1);
      afrag2(rb, r0, kh, a0);
      float16 accF, accG;
      const float bf = bs[32 + m], bg = bs[64 + m];
      #pragma unroll
      for (int r = 0; r < 16; r++) { accF[r] = bf; accG[r] = bg; }
      accF = MFMA_B16(a1[0], BW[0][0], accF);
      accF = MFMA_B16(a1[1], BW[0][1], accF);
      accF = MFMA_B16(a0[0], BW[1][0], accF);
      accF = MFMA_B16(a0[1], BW[1][1], accF);
      accG = MFMA_B16(a1[0], BW[2][0], accG);
      accG = MFMA_B16(a1[1], BW[2][1], accG);
      accG = MFMA_B16(a0[0], BW[3][0], accG);
      accG = MFMA_B16(a0[1], BW[3][1], accG);
      #pragma unroll
      for (int r = 0; r < 16; r++) {
        int row = (r & 3) + 8 * (r >> 2) + 4 * kh;
        int uf = R + row;
        if (uf < Wout) {
          float u = __expf(-2.f * accF[r]);
          float v = __expf(-accG[r]);
          float fg = (1.f - u) * __builtin_amdgcn_rcpf((1.f + u) * (1.f + v));
          xm[uf * 32 + m] = f2bs(fg);
        }
      }
      asm volatile("s_waitcnt lgkmcnt(0)" ::: "memory");

      // phase3: xnext = rbias + R@xmid + residual[row+1] (bf16 carry in C)
      int rx = R + m; if (rx > Wout - 1) rx = Wout - 1;
      short8 aX[2];
      afrag2(xm, rx, kh, aX);
      float16 accX;
      const float br = bs[96 + m];
      #pragma unroll
      for (int r = 0; r < 16; r++) {
        int row = (r & 3) + 8 * (r >> 2) + 4 * kh;
        int rr = R + row + 1; if (rr > Wout) rr = Wout;
        accX[r] = br + b2f(rb[rr * 32 + m]);
      }
      accX = MFMA_B16(aX[0], BW[4][0], accX);
      accX = MFMA_B16(aX[1], BW[4][1], accX);
      #pragma unroll
      for (int r = 0; r < 16; r++) {
        int row = (r & 3) + 8 * (r >> 2) + 4 * kh;
        int uf = R + row;
        if (uf < Wout) xbuf[uf * 32 + m] = f2bs(accX[r]);
      }
    } else if (newpf) {
      short* dst = bfw[(i + 1) & 1];
      #pragma unroll
      for (int q = 0; q < 7; q++) {
        int c = ptid + q * nP;
        if (c < 896) {
          short8 v;
          #pragma unroll
          for (int j = 0; j < 8; j++) v[j] = f2bs(pfn[q][j]);
          *(short8*)&dst[c * 8] = v;
        }
      }
      for (int t2 = ptid; t2 < 128; t2 += nP) {
        const float* bsrc = (t2 < 32) ? dil_b : (t2 < 64) ? filt_b : (t2 < 96) ? gate_b : res_b;
        bias2[(i + 1) & 1][t2] = bsrc[(i + 1) * 32 + (t2 & 31)];
      }
    }

    // commit scheme-A frags (layers 0-2 only)
    if (oldpf) {
      short* dst = bfw[(i + 1) & 1];
      #pragma unroll
      for (int q = 0; q < 4; q++) {
        if (q < nch) {
          short8 v;
          #pragma unroll
          for (int j = 0; j < 8; j++) v[j] = f2bs(pfo[q][j]);
          *(short8*)&dst[(tid + q * NT) * 8] = v;
        }
      }
      if (tid < 128) bias2[(i + 1) & 1][tid] = pbias;
    }
    __syncthreads();
    Win = Wout;
  }

  // ---- layers 11..15: in-register pipeline on wave 0 ----
  // x held as B-frag words xcur[8]: lane l holds X[t=l&31][c=16h+8kh+(0..7)],
  // word q of half h at xcur[4h+q]. D' = mfma(W_frag, X_frag) lands as
  // [c->regs (r&3)+8(r>>2)+4kh][t->lanes]; cvt_pk + shfl^32 re-forms B-frags.
  {
    const int t31 = lane & 31;
    const int hb  = lane & 32;
    unsigned xcur[8];
    if (wv == 0) {
      int tcl = t31 < Win - 1 ? t31 : Win - 1;    // Win==29 entering L11
      #pragma unroll
      for (int h = 0; h < 2; h++) {
        short8 v = *(const short8*)&xbuf[tcl * 32 + 16 * h + 8 * kh];
        union { short8 s; unsigned u[4]; } z; z.s = v;
        #pragma unroll
        for (int s = 0; s < 4; s++) xcur[4 * h + s] = z.u[s];
      }
    }

    #pragma unroll
    for (int i = 11; i < LL; i++) {
      const int d = 1 << (i & 3);
      const int Wout = Win - d - 1;
      const short* bw = bfw[i & 1];
      const float* bs = bias2[i & 1];

      // staging waves prefetch layer i+1 (scheme B, T=1 geometry)
      const bool npf = (i + 1 < LL) && (wv >= 1);
      const int ptid = tid - 64;
      float pfn[7][8];
      if (npf) {
        #pragma unroll
        for (int q = 0; q < 7; q++) {
          int c = ptid + q * 192;
          if (c < 896) load_chunk(i + 1, c, pfn[q], dil_w, filt_w, gate_w, res_w);
        }
      }

      if (wv == 0) {
        // weight A-frags (same LDS indices as old-path B-frags)
        short8 WA[7][2];
        #pragma unroll
        for (int mt = 0; mt < 7; mt++)
          #pragma unroll
          for (int h = 0; h < 2; h++)
            WA[mt][h] = *(const short8*)&bw[((mt * 2 + h) * 64 + lane) * 8];

        // ---- phase1: residual = db + W0.x[t+d] + W1.x[t] ----
        int td = t31 + d; if (td > Win - 1) td = Win - 1;
        int srcd = hb | td;
        unsigned xd[8];
        #pragma unroll
        for (int q = 0; q < 8; q++) xd[q] = (unsigned)__shfl((int)xcur[q], srcd);
        float16 acc;
        #pragma unroll
        for (int g = 0; g < 4; g++) {
          float4 b4 = *(const float4*)&bs[4 * kh + 8 * g];
          acc[4*g+0] = b4.x; acc[4*g+1] = b4.y; acc[4*g+2] = b4.z; acc[4*g+3] = b4.w;
        }
        acc = MFMA_B16(WA[0][0], mk8(xd[0], xd[1], xd[2], xd[3]), acc);
        acc = MFMA_B16(WA[0][1], mk8(xd[4], xd[5], xd[6], xd[7]), acc);
        acc = MFMA_B16(WA[1][0], mk8(xcur[0], xcur[1], xcur[2], xcur[3]), acc);
        acc = MFMA_B16(WA[1][1], mk8(xcur[4], xcur[5], xcur[6], xcur[7]), acc);

        // residual words + exchanges (unshifted cross, shift-1 own+cross)
        unsigned wrb[8], xc[8], x1[8], x1c[8];
        #pragma unroll
        for (int q = 0; q < 8; q++) wrb[q] = cvtpk(acc[2 * q], acc[2 * q + 1]);
        int t1 = t31 + 1; if (t1 > Wout) t1 = Wout;
        int s1o = hb | t1;
        int s1c = (hb ^ 32) | t1;
        #pragma unroll
        for (int q = 0; q < 8; q++) {
          xc[q]  = (unsigned)__shfl((int)wrb[q], lane ^ 32);
          x1[q]  = (unsigned)__shfl((int)wrb[q], s1o);
          x1c[q] = (unsigned)__shfl((int)wrb[q], s1c);
        }
        unsigned rb0w[8], rb1w[8];
        asmb(wrb, xc, kh, rb0w);
        asmb(x1, x1c, kh, rb1w);

        // ---- phase2: f/g convs + fused activation ----
        float16 accF, accG;
        #pragma unroll
        for (int g = 0; g < 4; g++) {
          float4 bF = *(const float4*)&bs[32 + 4 * kh + 8 * g];
          float4 bG = *(const float4*)&bs[64 + 4 * kh + 8 * g];
          accF[4*g+0] = bF.x; accF[4*g+1] = bF.y; accF[4*g+2] = bF.z; accF[4*g+3] = bF.w;
          accG[4*g+0] = bG.x; accG[4*g+1] = bG.y; accG[4*g+2] = bG.z; accG[4*g+3] = bG.w;
        }
        short8 RB10 = mk8(rb1w[0], rb1w[1], rb1w[2], rb1w[3]);
        short8 RB11 = mk8(rb1w[4], rb1w[5], rb1w[6], rb1w[7]);
        short8 RB00 = mk8(rb0w[0], rb0w[1], rb0w[2], rb0w[3]);
        short8 RB01 = mk8(rb0w[4], rb0w[5], rb0w[6], rb0w[7]);
        accF = MFMA_B16(WA[2][0], RB10, accF);
        accF = MFMA_B16(WA[2][1], RB11, accF);
        accF = MFMA_B16(WA[3][0], RB00, accF);
        accF = MFMA_B16(WA[3][1], RB01, accF);
        accG = MFMA_B16(WA[4][0], RB10, accG);
        accG = MFMA_B16(WA[4][1], RB11, accG);
        accG = MFMA_B16(WA[5][0], RB00, accG);
        accG = MFMA_B16(WA[5][1], RB01, accG);
        float fg[16];
        #pragma unroll
        for (int r = 0; r < 16; r++) {
          float u = __expf(-2.f * accF[r]);
          float v = __expf(-accG[r]);
          fg[r] = (1.f - u) * __builtin_amdgcn_rcpf((1.f + u) * (1.f + v));
        }
        unsigned wxm[8];
        #pragma unroll
        for (int q = 0; q < 8; q++) wxm[q] = cvtpk(fg[2 * q], fg[2 * q + 1]);

        if (i == LL - 1) {
          // spill gated row 0 (t=0 lives in lanes 0/32) for the tail
          if (t31 == 0) {
            #pragma unroll
            for (int q = 0; q < 8; q++) {
              int c0 = (2 * q & 3) + 8 * (q >> 1) + 4 * kh;
              *(unsigned*)&xm[c0] = wxm[q];
            }
          }
        } else {
          // ---- phase3: xnext = rbias + Wr.xm + residual[t+1] ----
          unsigned xmc[8];
          #pragma unroll
          for (int q = 0; q < 8; q++) xmc[q] = (unsigned)__shfl((int)wxm[q], lane ^ 32);
          unsigned xmw[8];
          asmb(wxm, xmc, kh, xmw);
          float16 accX;
          #pragma unroll
          for (int g = 0; g < 4; g++) {
            float4 bR = *(const float4*)&bs[96 + 4 * kh + 8 * g];
            #pragma unroll
            for (int j = 0; j < 4; j++) {
              int r = 4 * g + j;
              unsigned w = x1[r >> 1];
              float rv = (r & 1) ? u2f(w & 0xFFFF0000u) : u2f(w << 16);
              accX[r] = ((const float*)&bR)[j] + rv;
            }
          }
          accX = MFMA_B16(WA[6][0], mk8(xmw[0], xmw[1], xmw[2], xmw[3]), accX);
          accX = MFMA_B16(WA[6][1], mk8(xmw[4], xmw[5], xmw[6], xmw[7]), accX);
          unsigned wxn[8], xnc[8];
          #pragma unroll
          for (int q = 0; q < 8; q++) wxn[q] = cvtpk(accX[2 * q], accX[2 * q + 1]);
          #pragma unroll
          for (int q = 0; q < 8; q++) xnc[q] = (unsigned)__shfl((int)wxn[q], lane ^ 32);
          asmb(wxn, xnc, kh, xcur);
        }
      } else if (npf) {
        short* dst = bfw[(i + 1) & 1];
        #pragma unroll
        for (int q = 0; q < 7; q++) {
          int c = ptid + q * 192;
          if (c < 896) {
            short8 v;
            #pragma unroll
            for (int j = 0; j < 8; j++) v[j] = f2bs(pfn[q][j]);
            *(short8*)&dst[c * 8] = v;
          }
        }
        for (int t2 = ptid; t2 < 128; t2 += 192) {
          const float* bsrc = (t2 < 32) ? dil_b : (t2 < 64) ? filt_b : (t2 < 96) ? gate_b : res_b;
          bias2[(i + 1) & 1][t2] = bsrc[(i + 1) * 32 + (t2 & 31)];
        }
      }
      __syncthreads();
      Win = Wout;
    }
  }

  // ---- tail (f32 VALU, 4 waves): skip(l15) -> end1 -> end2 -> fc1..fc4 ----
  {
    float acc = skip_b[15 * 256 + tid];
    const float* wr = skip_w + (15 * 256 + tid) * 32;
    #pragma unroll
    for (int k = 0; k < 32; k += 4) {
      float4 w = *(const float4*)&wr[k];
      acc += (w.x * b2f(xm[k]) + w.y * b2f(xm[k+1])) + (w.z * b2f(xm[k+2]) + w.w * b2f(xm[k+3]));
    }
    vecA[tid] = fmaxf(acc, 0.f);
  }
  __syncthreads();
  {
    const float* wr = end1_w + tid * 256;
    float a4[4] = {0.f, 0.f, 0.f, 0.f};
    #pragma unroll 4
    for (int k = 0; k < 256; k += 16) {
      #pragma unroll
      for (int q = 0; q < 4; q++) {
        float4 w = *(const float4*)&wr[k + 4 * q];
        float4 a = *(const float4*)&vecA[k + 4 * q];
        a4[q] += (w.x * a.x + w.y * a.y) + (w.z * a.z + w.w * a.w);
      }
    }
    vecB[tid] = fmaxf(end1_b[tid] + (a4[0] + a4[1]) + (a4[2] + a4[3]), 0.f);
  }
  __syncthreads();
  float h2;
  {
    const float* wr = end2_w + tid * 256;
    float a4[4] = {0.f, 0.f, 0.f, 0.f};
    #pragma unroll 4
    for (int k = 0; k < 256; k += 16) {
      #pragma unroll
      for (int q = 0; q < 4; q++) {
        float4 w = *(const float4*)&wr[k + 4 * q];
        float4 a = *(const float4*)&vecB[k + 4 * q];
        a4[q] += (w.x * a.x + w.y * a.y) + (w.z * a.z + w.w * a.w);
      }
    }
    h2 = end2_b[tid] + (a4[0] + a4[1]) + (a4[2] + a4[3]);
  }
  __syncthreads();
  vecA[tid] = h2;
  __syncthreads();
  if (tid < 128) {
    const float* wr = fc1_w + tid * 256;
    float a4[4] = {0.f, 0.f, 0.f, 0.f};
    #pragma unroll 4
    for (int k = 0; k < 256; k += 16) {
      #pragma unroll
      for (int q = 0; q < 4; q++) {
        float4 w = *(const float4*)&wr[k + 4 * q];
        float4 a = *(const float4*)&vecA[k + 4 * q];
        a4[q] += (w.x * a.x + w.y * a.y) + (w.z * a.z + w.w * a.w);
      }
    }
    vecB[tid] = fmaxf(fc1_b[tid] + (a4[0] + a4[1]) + (a4[2] + a4[3]), 0.f);
  }
  __syncthreads();
  if (tid < 128) {
    const float* wr = fc2_w + tid * 128;
    float a4[4] = {0.f, 0.f, 0.f, 0.f};
    #pragma unroll 2
    for (int k = 0; k < 128; k += 16) {
      #pragma unroll
      for (int q = 0; q < 4; q++) {
        float4 w = *(const float4*)&wr[k + 4 * q];
        float4 a = *(const float4*)&vecB[k + 4 * q];
        a4[q] += (w.x * a.x + w.y * a.y) + (w.z * a.z + w.w * a.w);
      }
    }
    vecA[tid] = fmaxf(fc2_b[tid] + (a4[0] + a4[1]) + (a4[2] + a4[3]), 0.f);
  }
  __syncthreads();
  if (tid < 64) {
    const float* wr = fc3_w + tid * 128;
    float a4[4] = {0.f, 0.f, 0.f, 0.f};
    #pragma unroll 2
    for (int k = 0; k < 128; k += 16) {
      #pragma unroll
      for (int q = 0; q < 4; q++) {
        float4 w = *(const float4*)&wr[k + 4 * q];
        float4 a = *(const float4*)&vecA[k + 4 * q];
        a4[q] += (w.x * a.x + w.y * a.y) + (w.z * a.z + w.w * a.w);
      }
    }
    vecB[tid] = fmaxf(fc3_b[tid] + (a4[0] + a4[1]) + (a4[2] + a4[3]), 0.f);
  }
  __syncthreads();
  {
    const float* wr = fc4_w + tid * 64;
    float a4[4] = {0.f, 0.f, 0.f, 0.f};
    #pragma unroll
    for (int k = 0; k < 64; k += 16) {
      #pragma unroll
      for (int q = 0; q < 4; q++) {
        float4 w = *(const float4*)&wr[k + 4 * q];
        float4 a = *(const float4*)&vecB[k + 4 * q];
        a4[q] += (w.x * a.x + w.y * a.y) + (w.z * a.z + w.w * a.w);
      }
    }
    out[b * 256 + tid] = fc4_b[tid] + (a4[0] + a4[1]) + (a4[2] + a4[3]);
  }
}

extern "C" void kernel_launch(void* const* d_in, const int* in_sizes, int n_in,
                              void* d_out, int out_size, void* d_ws, size_t ws_size,
                              hipStream_t stream) {
  wavenet_kernel<<<BB, NT, 0, stream>>>(
      (const int*)d_in[0],    (const float*)d_in[1],  (const float*)d_in[2],  (const float*)d_in[3],
      (const float*)d_in[4],  (const float*)d_in[5],  (const float*)d_in[6],  (const float*)d_in[7],
      (const float*)d_in[8],  (const float*)d_in[9],  (const float*)d_in[10], (const float*)d_in[11],
      (const float*)d_in[12], (const float*)d_in[13], (const float*)d_in[14], (const float*)d_in[15],
      (const float*)d_in[16], (const float*)d_in[17], (const float*)d_in[18], (const float*)d_in[19],
      (const float*)d_in[20], (const float*)d_in[21], (const float*)d_in[22], (const float*)d_in[23],
      (const float*)d_in[24], (const float*)d_in[25], (float*)d_out);
}

// Round 3
// 204.908 us; speedup vs baseline: 1.0333x; 1.0003x over previous
//
#include <hip/hip_runtime.h>

// WaveNet inference on MFMA. Exploits: (1) only last timestep feeds the FC
// head, (2) skip overwritten each layer (only layer 15's matters),
// (3) receptive field at t=T-1 is 77 steps.
// Round 16 = R15 +
//  - stride-31 OVERLAPPING tiles for LDS layers (i=0..9): wave w owns rb
//    rows [31w,31w+31]; phase2/3 outputs [31w,31w+30] need only own-tile
//    rb/xm -> the mid __syncthreads is gone (wave-local lgkmcnt chains),
//    ONE barrier per layer. Boundary row computed redundantly by both
//    waves (bit-identical). xbuf double-buffered (in-place race otherwise).
//  - L10 joins the in-register path: rows 32,33 of its input stashed in
//    broadcast regs e32/e33; dilated-tap shuffle overridden on lanes>=28.
//  - tail: unroll 8 (32 loads in flight; VGPR budget 512 at 1 wave/SIMD),
//    redundant barrier pair around h2 store removed.
// Regime rules learned (R3/4: >256 thr spills; R8: never trade CUs for
// waves; R9/R11: no serial work to kill barriers; R12: reg plumbing ~ LDS;
// R14: staging off compute waves ~neutral; R15: de-LDS'ing a layer ~0.8us).

#define BB 16
#define TT 8192
#define LL 16
#define W0 77
#define NT 256

typedef __attribute__((ext_vector_type(8)))  short short8;
typedef __attribute__((ext_vector_type(16))) float float16;

#define MFMA_B16(a, b, c) __builtin_amdgcn_mfma_f32_32x32x16_bf16(a, b, c, 0, 0, 0)

__device__ __forceinline__ short f2bs(float f) {   // f32 -> bf16 bits, RNE
  union { float ff; unsigned u; } v; v.ff = f;
  unsigned u = v.u;
  return (short)((u + 0x7FFFu + ((u >> 16) & 1u)) >> 16);
}
__device__ __forceinline__ float b2f(short h) {
  union { unsigned u; float f; } v;
  v.u = ((unsigned)(unsigned short)h) << 16; return v.f;
}
__device__ __forceinline__ unsigned cvtpk(float lo, float hi) {
  unsigned r;
  asm("v_cvt_pk_bf16_f32 %0, %1, %2" : "=v"(r) : "v"(lo), "v"(hi));
  return r;
}
__device__ __forceinline__ short8 mk8(unsigned a, unsigned b, unsigned c, unsigned d) {
  union { unsigned u[4]; short8 s; } z;
  z.u[0] = a; z.u[1] = b; z.u[2] = c; z.u[3] = d; return z.s;
}
__device__ __forceinline__ float u2f(unsigned u) {
  union { unsigned x; float f; } z; z.x = u; return z.f;
}
// Assemble next-phase B-frag words from own packed D'-words + cross-half
// words (from lane^32). own[q]=pack(acc[2q],acc[2q+1]) holds c=(2q&3)+8*(q>>1)+4kh.
__device__ __forceinline__ void asmb(const unsigned* own, const unsigned* cr,
                                     int kh, unsigned* o) {
  #pragma unroll
  for (int h = 0; h < 2; h++) {
    o[4*h+0] = kh ? cr[4*h+2] : own[4*h+0];
    o[4*h+1] = kh ? cr[4*h+3] : own[4*h+1];
    o[4*h+2] = kh ? own[4*h+2] : cr[4*h+0];
    o[4*h+3] = kh ? own[4*h+3] : cr[4*h+1];
  }
}

// A-fragment halves from [row][32] bf16 LDS: A[m][k], k-local=(lane>>5)*8+j.
__device__ __forceinline__ void afrag2(const short* src, int row, int kh, short8* out) {
  out[0] = *(const short8*)&src[row * 32 + 8 * kh];
  out[1] = *(const short8*)&src[row * 32 + 16 + 8 * kh];
}

// load a full row's 8 packed words (B-frag layout) from [row][32] bf16 LDS
__device__ __forceinline__ void ldrow(const short* xb, int row, int kh, unsigned* w8) {
  #pragma unroll
  for (int h = 0; h < 2; h++) {
    short8 v = *(const short8*)&xb[row * 32 + 16 * h + 8 * kh];
    union { short8 s; unsigned u[4]; } z; z.s = v;
    #pragma unroll
    for (int s = 0; s < 4; s++) w8[4 * h + s] = z.u[s];
  }
}

// chunk cid in [0,896): mat=cid>>7, h=(cid>>6)&1, ln=cid&63 -> n=ln&31,k2=ln>>5
// value j: W[16h+8k2+j][n] of matrix mat; dst offset = cid*8 shorts (b128).
__device__ __forceinline__ void load_chunk(
    int li, int cid, float* pf,
    const float* dil_w, const float* filt_w, const float* gate_w, const float* res_w)
{
  int mat = cid >> 7;
  int h = (cid >> 6) & 1, ln = cid & 63;
  int n = ln & 31, k2 = ln >> 5;
  int base = (li * 32 + n) * 32 + 16 * h + 8 * k2;
  if (mat == 6) {
    const float* p = res_w + base;
    #pragma unroll
    for (int j = 0; j < 8; j++) pf[j] = p[j];
  } else {
    const float* w = (mat < 2) ? dil_w : (mat < 4) ? filt_w : gate_w;
    const float* p = w + base * 2 + (mat & 1);
    #pragma unroll
    for (int j = 0; j < 8; j++) pf[j] = p[2 * j];
  }
}

__global__ __launch_bounds__(NT, 1) void wavenet_kernel(
    const int* __restrict__ tokens,
    const float* __restrict__ emb,
    const float* __restrict__ init_w, const float* __restrict__ init_b,
    const float* __restrict__ dil_w,  const float* __restrict__ dil_b,
    const float* __restrict__ filt_w, const float* __restrict__ filt_b,
    const float* __restrict__ gate_w, const float* __restrict__ gate_b,
    const float* __restrict__ res_w,  const float* __restrict__ res_b,
    const float* __restrict__ skip_w, const float* __restrict__ skip_b,
    const float* __restrict__ end1_w, const float* __restrict__ end1_b,
    const float* __restrict__ end2_w, const float* __restrict__ end2_b,
    const float* __restrict__ fc1_w,  const float* __restrict__ fc1_b,
    const float* __restrict__ fc2_w,  const float* __restrict__ fc2_b,
    const float* __restrict__ fc3_w,  const float* __restrict__ fc3_b,
    const float* __restrict__ fc4_w,  const float* __restrict__ fc4_b,
    float* __restrict__ out)
{
  __shared__ __align__(16) short bfw[2][7168];   // weight frags, double buffer
  __shared__ __align__(16) float bias2[2][128];
  __shared__ __align__(16) short xbuf[2][W0 * 32];  // activation double buffer
  __shared__ __align__(16) short pool[8624];     // emb stage (init) / rb+xm
  __shared__ int tok[W0];
  __shared__ __align__(16) float vecA[256], vecB[256];

  short* rb = pool;          // 76*32
  short* xm = pool + 2432;   // 76*32

  const int tid  = threadIdx.x;
  const int lane = tid & 63;
  const int wv   = tid >> 6;
  const int m    = lane & 31;
  const int kh   = lane >> 5;
  const int b    = blockIdx.x;

  // ---- tokens ----
  if (tid < W0) tok[tid] = tokens[b * TT + (TT - 1 - tid)];
  __syncthreads();

  // ---- stage emb rows (bf16, rows zero-padded to K=112) ----
  for (int cid = tid; cid < 77 * 14; cid += NT) {
    int u = cid / 14, s = cid % 14;
    const float* er = emb + tok[u] * 100 + s * 8;
    short8 v;
    if (s < 12) {
      #pragma unroll
      for (int j = 0; j < 8; j++) v[j] = f2bs(er[j]);
    } else if (s == 12) {
      #pragma unroll
      for (int j = 0; j < 4; j++) v[j] = f2bs(er[j]);
      #pragma unroll
      for (int j = 4; j < 8; j++) v[j] = 0;
    } else {
      #pragma unroll
      for (int j = 0; j < 8; j++) v[j] = 0;
    }
    *(short8*)&pool[u * 112 + s * 8] = v;
  }
  // stage layer-0 weight frags + biases directly (all threads)
  for (int cid = tid; cid < 896; cid += NT) {
    float pf[8];
    load_chunk(0, cid, pf, dil_w, filt_w, gate_w, res_w);
    short8 v;
    #pragma unroll
    for (int j = 0; j < 8; j++) v[j] = f2bs(pf[j]);
    *(short8*)&bfw[0][cid * 8] = v;
  }
  if (tid < 128) {
    const float* bsrc = (tid < 32) ? dil_b : (tid < 64) ? filt_b : (tid < 96) ? gate_b : res_b;
    bias2[0][tid] = bsrc[tid & 31];
  }
  __syncthreads();

  // ---- init conv (waves 0..2, one 32-row tile each, MFMA over K=112) ----
  if (wv < 3) {
    short8 bi[7];
    #pragma unroll
    for (int s = 0; s < 7; s++) {
      const float* p = init_w + m * 100 + s * 16 + kh * 8;
      short8 v;
      if (s < 6) {
        #pragma unroll
        for (int j = 0; j < 8; j++) v[j] = f2bs(p[j]);
      } else if (kh == 0) {
        #pragma unroll
        for (int j = 0; j < 4; j++) v[j] = f2bs(p[j]);
        #pragma unroll
        for (int j = 4; j < 8; j++) v[j] = 0;
      } else {
        #pragma unroll
        for (int j = 0; j < 8; j++) v[j] = 0;
      }
      bi[s] = v;
    }
    const float binit = init_b[m];
    const int R = wv * 32;
    int u = R + m; if (u > 76) u = 76;
    float16 acc;
    #pragma unroll
    for (int r = 0; r < 16; r++) acc[r] = binit;
    #pragma unroll
    for (int s = 0; s < 7; s++) {
      short8 a = *(const short8*)&pool[u * 112 + s * 16 + kh * 8];
      acc = MFMA_B16(a, bi[s], acc);
    }
    #pragma unroll
    for (int r = 0; r < 16; r++) {
      int row = (r & 3) + 8 * (r >> 2) + 4 * kh;
      int uu = R + row;
      if (uu < W0) xbuf[0][uu * 32 + m] = f2bs(acc[r]);
    }
  }
  __syncthreads();

  // ---- layers 0..9 (LDS pipeline, stride-31 overlapping tiles, 1 barrier) ----
  int Win = W0;
  for (int i = 0; i < 10; i++) {
    const int d = 1 << (i & 3);
    const int Wout = Win - d - 1;
    const int T = (Wout + 31) / 31;        // overlapping-tile count (same values as before)
    const short* bw = bfw[i & 1];
    const float* bs = bias2[i & 1];
    const short* xin  = xbuf[i & 1];
    short* xout = xbuf[(i + 1) & 1];

    // -- prefetch scheme A (layers 0-2, T==3): all threads, regs, commit
    float pfo[4][8];
    float pbias = 0.f;
    const int nch = (tid < 128) ? 4 : 3;   // 896 = 3*256 + 128
    const bool oldpf = (T >= 3) && (i + 1 < LL);
    if (oldpf) {
      #pragma unroll
      for (int q = 0; q < 4; q++) {
        if (q < nch)
          load_chunk(i + 1, tid + q * NT, pfo[q], dil_w, filt_w, gate_w, res_w);
      }
      if (tid < 128) {
        const float* bsrc = (tid < 32) ? dil_b : (tid < 64) ? filt_b : (tid < 96) ? gate_b : res_b;
        pbias = bsrc[(i + 1) * 32 + (tid & 31)];
      }
    }
    // -- prefetch scheme B (T<=2): waves wv>=T carry the whole staging.
    const bool newpf = (T <= 2) && (i + 1 < LL) && (wv >= T);
    const int nP = NT - T * 64;            // 128 (T==2)
    const int ptid = tid - T * 64;
    float pfn[7][8];
    if (newpf) {
      #pragma unroll
      for (int q = 0; q < 7; q++) {
        int c = ptid + q * nP;
        if (c < 896) load_chunk(i + 1, c, pfn[q], dil_w, filt_w, gate_w, res_w);
      }
    }

    if (wv < T) {
      const int R = wv * 31;
      // B-frags for all phases (weight buffer stable from layer top)
      short8 B0[2], B1[2], BW[5][2];
      #pragma unroll
      for (int h = 0; h < 2; h++) {
        B0[h] = *(const short8*)&bw[((0 * 2 + h) * 64 + lane) * 8];
        B1[h] = *(const short8*)&bw[((1 * 2 + h) * 64 + lane) * 8];
      }
      #pragma unroll
      for (int mt = 0; mt < 5; mt++)
        #pragma unroll
        for (int h = 0; h < 2; h++)
          BW[mt][h] = *(const short8*)&bw[(((mt + 2) * 2 + h) * 64 + lane) * 8];

      // ---- phase1: rb rows R..R+31 (boundary row redundant across waves) ----
      int vra = R + m + d; if (vra > Win - 1) vra = Win - 1;
      int vrz = R + m;     if (vrz > Win - 1) vrz = Win - 1;
      short8 aA[2], aZ[2];
      afrag2(xin, vra, kh, aA);
      afrag2(xin, vrz, kh, aZ);
      float16 acc;
      const float bc = bs[m];
      #pragma unroll
      for (int r = 0; r < 16; r++) acc[r] = bc;
      acc = MFMA_B16(aA[0], B0[0], acc);
      acc = MFMA_B16(aA[1], B0[1], acc);
      acc = MFMA_B16(aZ[0], B1[0], acc);
      acc = MFMA_B16(aZ[1], B1[1], acc);
      #pragma unroll
      for (int r = 0; r < 16; r++) {
        int row = (r & 3) + 8 * (r >> 2) + 4 * kh;
        int vr = R + row;
        if (vr <= Wout) rb[vr * 32 + m] = f2bs(acc[r]);
      }
      asm volatile("s_waitcnt lgkmcnt(0)" ::: "memory");  // wave-local P1->P2

      // ---- phase2: f/g convs; outputs rows R..R+30, own-tile rb only ----
      const int capA = (R + 31 < Wout) ? (R + 31) : Wout;
      int r1 = R + m + 1; if (r1 > capA) r1 = capA;
      int r0 = R + m;     if (r0 > Wout) r0 = Wout;
      short8 a1[2], a0[2];
      afrag2(rb, r1, kh, a1);
      afrag2(rb, r0, kh, a0);
      float16 accF, accG;
      const float bf = bs[32 + m], bg = bs[64 + m];
      #pragma unroll
      for (int r = 0; r < 16; r++) { accF[r] = bf; accG[r] = bg; }
      accF = MFMA_B16(a1[0], BW[0][0], accF);
      accF = MFMA_B16(a1[1], BW[0][1], accF);
      accF = MFMA_B16(a0[0], BW[1][0], accF);
      accF = MFMA_B16(a0[1], BW[1][1], accF);
      accG = MFMA_B16(a1[0], BW[2][0], accG);
      accG = MFMA_B16(a1[1], BW[2][1], accG);
      accG = MFMA_B16(a0[0], BW[3][0], accG);
      accG = MFMA_B16(a0[1], BW[3][1], accG);
      #pragma unroll
      for (int r = 0; r < 16; r++) {
        int row = (r & 3) + 8 * (r >> 2) + 4 * kh;
        int uf = R + row;
        if (row < 31 && uf < Wout) {
          float u = __expf(-2.f * accF[r]);
          float v = __expf(-accG[r]);
          float fg = (1.f - u) * __builtin_amdgcn_rcpf((1.f + u) * (1.f + v));
          xm[uf * 32 + m] = f2bs(fg);
        }
      }
      asm volatile("s_waitcnt lgkmcnt(0)" ::: "memory");  // wave-local P2->P3

      // ---- phase3: xnext = rbias + R@xmid + rb[row+1] (own-tile xm/rb) ----
      const int capX = (R + 30 < Wout - 1) ? (R + 30) : (Wout - 1);
      int rx = R + m; if (rx > capX) rx = capX;
      short8 aX[2];
      afrag2(xm, rx, kh, aX);
      float16 accX;
      const float br = bs[96 + m];
      #pragma unroll
      for (int r = 0; r < 16; r++) {
        int row = (r & 3) + 8 * (r >> 2) + 4 * kh;
        int rr = R + row + 1; if (rr > Wout) rr = Wout;   // row==31 case discarded
        accX[r] = br + b2f(rb[rr * 32 + m]);
      }
      accX = MFMA_B16(aX[0], BW[4][0], accX);
      accX = MFMA_B16(aX[1], BW[4][1], accX);
      #pragma unroll
      for (int r = 0; r < 16; r++) {
        int row = (r & 3) + 8 * (r >> 2) + 4 * kh;
        int uf = R + row;
        if (row < 31 && uf < Wout) xout[uf * 32 + m] = f2bs(accX[r]);
      }
    } else if (newpf) {
      short* dst = bfw[(i + 1) & 1];
      #pragma unroll
      for (int q = 0; q < 7; q++) {
        int c = ptid + q * nP;
        if (c < 896) {
          short8 v;
          #pragma unroll
          for (int j = 0; j < 8; j++) v[j] = f2bs(pfn[q][j]);
          *(short8*)&dst[c * 8] = v;
        }
      }
      for (int t2 = ptid; t2 < 128; t2 += nP) {
        const float* bsrc = (t2 < 32) ? dil_b : (t2 < 64) ? filt_b : (t2 < 96) ? gate_b : res_b;
        bias2[(i + 1) & 1][t2] = bsrc[(i + 1) * 32 + (t2 & 31)];
      }
    }

    // commit scheme-A frags (layers 0-2 only)
    if (oldpf) {
      short* dst = bfw[(i + 1) & 1];
      #pragma unroll
      for (int q = 0; q < 4; q++) {
        if (q < nch) {
          short8 v;
          #pragma unroll
          for (int j = 0; j < 8; j++) v[j] = f2bs(pfo[q][j]);
          *(short8*)&dst[(tid + q * NT) * 8] = v;
        }
      }
      if (tid < 128) bias2[(i + 1) & 1][tid] = pbias;
    }
    __syncthreads();                        // single barrier per layer
    Win = Wout;
  }

  // ---- layers 10..15: in-register pipeline on wave 0 ----
  // x held as B-frag words xcur[8]: lane l holds X[t=l&31][c=16h+8kh+(0..7)].
  // L10 (Win=34): rows 32,33 stashed in broadcast regs e32/e33; dilated-tap
  // shuffle overridden on lanes with t+4 >= 32.
  {
    const int t31 = lane & 31;
    const int hb  = lane & 32;
    unsigned xcur[8], e32[8], e33[8];
    if (wv == 0) {
      const short* xb0 = xbuf[0];          // L9 wrote xbuf[(9+1)&1] = [0]
      int tcl = t31 < Win - 1 ? t31 : Win - 1;    // Win==34: tcl = t31
      ldrow(xb0, tcl, kh, xcur);
      ldrow(xb0, 32, kh, e32);
      ldrow(xb0, 33, kh, e33);
    }

    #pragma unroll
    for (int i = 10; i < LL; i++) {
      const int d = 1 << (i & 3);
      const int Wout = Win - d - 1;
      const short* bw = bfw[i & 1];
      const float* bs = bias2[i & 1];

      // staging waves prefetch layer i+1 (scheme B, T=1 geometry)
      const bool npf = (i + 1 < LL) && (wv >= 1);
      const int ptid = tid - 64;
      float pfn[7][8];
      if (npf) {
        #pragma unroll
        for (int q = 0; q < 7; q++) {
          int c = ptid + q * 192;
          if (c < 896) load_chunk(i + 1, c, pfn[q], dil_w, filt_w, gate_w, res_w);
        }
      }

      if (wv == 0) {
        // weight A-frags (same LDS indices as old-path B-frags)
        short8 WA[7][2];
        #pragma unroll
        for (int mt = 0; mt < 7; mt++)
          #pragma unroll
          for (int h = 0; h < 2; h++)
            WA[mt][h] = *(const short8*)&bw[((mt * 2 + h) * 64 + lane) * 8];

        // ---- phase1: residual = db + W0.x[t+d] + W1.x[t] ----
        unsigned xd[8];
        if (i == 10) {
          int td = t31 + d;                 // d=4: lanes 28..31 -> 32..35
          int ts = td > 31 ? 31 : td;
          #pragma unroll
          for (int q = 0; q < 8; q++) {
            unsigned s = (unsigned)__shfl((int)xcur[q], hb | ts);
            s = (td == 32) ? e32[q] : s;
            s = (td >= 33) ? e33[q] : s;    // clamp Win-1 = 33
            xd[q] = s;
          }
        } else {
          int td = t31 + d; if (td > Win - 1) td = Win - 1;
          int srcd = hb | td;
          #pragma unroll
          for (int q = 0; q < 8; q++) xd[q] = (unsigned)__shfl((int)xcur[q], srcd);
        }
        float16 acc;
        #pragma unroll
        for (int g = 0; g < 4; g++) {
          float4 b4 = *(const float4*)&bs[4 * kh + 8 * g];
          acc[4*g+0] = b4.x; acc[4*g+1] = b4.y; acc[4*g+2] = b4.z; acc[4*g+3] = b4.w;
        }
        acc = MFMA_B16(WA[0][0], mk8(xd[0], xd[1], xd[2], xd[3]), acc);
        acc = MFMA_B16(WA[0][1], mk8(xd[4], xd[5], xd[6], xd[7]), acc);
        acc = MFMA_B16(WA[1][0], mk8(xcur[0], xcur[1], xcur[2], xcur[3]), acc);
        acc = MFMA_B16(WA[1][1], mk8(xcur[4], xcur[5], xcur[6], xcur[7]), acc);

        // residual words + exchanges (unshifted cross, shift-1 own+cross)
        unsigned wrb[8], xc[8], x1[8], x1c[8];
        #pragma unroll
        for (int q = 0; q < 8; q++) wrb[q] = cvtpk(acc[2 * q], acc[2 * q + 1]);
        int t1 = t31 + 1; if (t1 > Wout) t1 = Wout;
        int s1o = hb | t1;
        int s1c = (hb ^ 32) | t1;
        #pragma unroll
        for (int q = 0; q < 8; q++) {
          xc[q]  = (unsigned)__shfl((int)wrb[q], lane ^ 32);
          x1[q]  = (unsigned)__shfl((int)wrb[q], s1o);
          x1c[q] = (unsigned)__shfl((int)wrb[q], s1c);
        }
        unsigned rb0w[8], rb1w[8];
        asmb(wrb, xc, kh, rb0w);
        asmb(x1, x1c, kh, rb1w);

        // ---- phase2: f/g convs + fused activation ----
        float16 accF, accG;
        #pragma unroll
        for (int g = 0; g < 4; g++) {
          float4 bF = *(const float4*)&bs[32 + 4 * kh + 8 * g];
          float4 bG = *(const float4*)&bs[64 + 4 * kh + 8 * g];
          accF[4*g+0] = bF.x; accF[4*g+1] = bF.y; accF[4*g+2] = bF.z; accF[4*g+3] = bF.w;
          accG[4*g+0] = bG.x; accG[4*g+1] = bG.y; accG[4*g+2] = bG.z; accG[4*g+3] = bG.w;
        }
        short8 RB10 = mk8(rb1w[0], rb1w[1], rb1w[2], rb1w[3]);
        short8 RB11 = mk8(rb1w[4], rb1w[5], rb1w[6], rb1w[7]);
        short8 RB00 = mk8(rb0w[0], rb0w[1], rb0w[2], rb0w[3]);
        short8 RB01 = mk8(rb0w[4], rb0w[5], rb0w[6], rb0w[7]);
        accF = MFMA_B16(WA[2][0], RB10, accF);
        accF = MFMA_B16(WA[2][1], RB11, accF);
        accF = MFMA_B16(WA[3][0], RB00, accF);
        accF = MFMA_B16(WA[3][1], RB01, accF);
        accG = MFMA_B16(WA[4][0], RB10, accG);
        accG = MFMA_B16(WA[4][1], RB11, accG);
        accG = MFMA_B16(WA[5][0], RB00, accG);
        accG = MFMA_B16(WA[5][1], RB01, accG);
        float fg[16];
        #pragma unroll
        for (int r = 0; r < 16; r++) {
          float u = __expf(-2.f * accF[r]);
          float v = __expf(-accG[r]);
          fg[r] = (1.f - u) * __builtin_amdgcn_rcpf((1.f + u) * (1.f + v));
        }
        unsigned wxm[8];
        #pragma unroll
        for (int q = 0; q < 8; q++) wxm[q] = cvtpk(fg[2 * q], fg[2 * q + 1]);

        if (i == LL - 1) {
          // spill gated row 0 (t=0 lives in lanes 0/32) for the tail
          if (t31 == 0) {
            #pragma unroll
            for (int q = 0; q < 8; q++) {
              int c0 = (2 * q & 3) + 8 * (q >> 1) + 4 * kh;
              *(unsigned*)&xm[c0] = wxm[q];
            }
          }
        } else {
          // ---- phase3: xnext = rbias + Wr.xm + residual[t+1] ----
          unsigned xmc[8];
          #pragma unroll
          for (int q = 0; q < 8; q++) xmc[q] = (unsigned)__shfl((int)wxm[q], lane ^ 32);
          unsigned xmw[8];
          asmb(wxm, xmc, kh, xmw);
          float16 accX;
          #pragma unroll
          for (int g = 0; g < 4; g++) {
            float4 bR = *(const float4*)&bs[96 + 4 * kh + 8 * g];
            #pragma unroll
            for (int j = 0; j < 4; j++) {
              int r = 4 * g + j;
              unsigned w = x1[r >> 1];
              float rv = (r & 1) ? u2f(w & 0xFFFF0000u) : u2f(w << 16);
              accX[r] = ((const float*)&bR)[j] + rv;
            }
          }
          accX = MFMA_B16(WA[6][0], mk8(xmw[0], xmw[1], xmw[2], xmw[3]), accX);
          accX = MFMA_B16(WA[6][1], mk8(xmw[4], xmw[5], xmw[6], xmw[7]), accX);
          unsigned wxn[8], xnc[8];
          #pragma unroll
          for (int q = 0; q < 8; q++) wxn[q] = cvtpk(accX[2 * q], accX[2 * q + 1]);
          #pragma unroll
          for (int q = 0; q < 8; q++) xnc[q] = (unsigned)__shfl((int)wxn[q], lane ^ 32);
          asmb(wxn, xnc, kh, xcur);
        }
      } else if (npf) {
        short* dst = bfw[(i + 1) & 1];
        #pragma unroll
        for (int q = 0; q < 7; q++) {
          int c = ptid + q * 192;
          if (c < 896) {
            short8 v;
            #pragma unroll
            for (int j = 0; j < 8; j++) v[j] = f2bs(pfn[q][j]);
            *(short8*)&dst[c * 8] = v;
          }
        }
        for (int t2 = ptid; t2 < 128; t2 += 192) {
          const float* bsrc = (t2 < 32) ? dil_b : (t2 < 64) ? filt_b : (t2 < 96) ? gate_b : res_b;
          bias2[(i + 1) & 1][t2] = bsrc[(i + 1) * 32 + (t2 & 31)];
        }
      }
      __syncthreads();
      Win = Wout;
    }
  }

  // ---- tail (f32 VALU, 4 waves): skip(l15) -> end1 -> end2 -> fc1..fc4 ----
  {
    float acc = skip_b[15 * 256 + tid];
    const float* wr = skip_w + (15 * 256 + tid) * 32;
    #pragma unroll
    for (int k = 0; k < 32; k += 4) {
      float4 w = *(const float4*)&wr[k];
      acc += (w.x * b2f(xm[k]) + w.y * b2f(xm[k+1])) + (w.z * b2f(xm[k+2]) + w.w * b2f(xm[k+3]));
    }
    vecA[tid] = fmaxf(acc, 0.f);
  }
  __syncthreads();
  {
    const float* wr = end1_w + tid * 256;
    float a4[4] = {0.f, 0.f, 0.f, 0.f};
    #pragma unroll 8
    for (int k = 0; k < 256; k += 16) {
      #pragma unroll
      for (int q = 0; q < 4; q++) {
        float4 w = *(const float4*)&wr[k + 4 * q];
        float4 a = *(const float4*)&vecA[k + 4 * q];
        a4[q] += (w.x * a.x + w.y * a.y) + (w.z * a.z + w.w * a.w);
      }
    }
    vecB[tid] = fmaxf(end1_b[tid] + (a4[0] + a4[1]) + (a4[2] + a4[3]), 0.f);
  }
  __syncthreads();
  {
    const float* wr = end2_w + tid * 256;
    float a4[4] = {0.f, 0.f, 0.f, 0.f};
    #pragma unroll 8
    for (int k = 0; k < 256; k += 16) {
      #pragma unroll
      for (int q = 0; q < 4; q++) {
        float4 w = *(const float4*)&wr[k + 4 * q];
        float4 a = *(const float4*)&vecB[k + 4 * q];
        a4[q] += (w.x * a.x + w.y * a.y) + (w.z * a.z + w.w * a.w);
      }
    }
    float h2 = end2_b[tid] + (a4[0] + a4[1]) + (a4[2] + a4[3]);
    vecA[tid] = h2;   // safe: vecA readers (end1) all past the last barrier
  }
  __syncthreads();
  if (tid < 128) {
    const float* wr = fc1_w + tid * 256;
    float a4[4] = {0.f, 0.f, 0.f, 0.f};
    #pragma unroll 8
    for (int k = 0; k < 256; k += 16) {
      #pragma unroll
      for (int q = 0; q < 4; q++) {
        float4 w = *(const float4*)&wr[k + 4 * q];
        float4 a = *(const float4*)&vecA[k + 4 * q];
        a4[q] += (w.x * a.x + w.y * a.y) + (w.z * a.z + w.w * a.w);
      }
    }
    vecB[tid] = fmaxf(fc1_b[tid] + (a4[0] + a4[1]) + (a4[2] + a4[3]), 0.f);
  }
  __syncthreads();
  if (tid < 128) {
    const float* wr = fc2_w + tid * 128;
    float a4[4] = {0.f, 0.f, 0.f, 0.f};
    #pragma unroll 4
    for (int k = 0; k < 128; k += 16) {
      #pragma unroll
      for (int q = 0; q < 4; q++) {
        float4 w = *(const float4*)&wr[k + 4 * q];
        float4 a = *(const float4*)&vecB[k + 4 * q];
        a4[q] += (w.x * a.x + w.y * a.y) + (w.z * a.z + w.w * a.w);
      }
    }
    vecA[tid] = fmaxf(fc2_b[tid] + (a4[0] + a4[1]) + (a4[2] + a4[3]), 0.f);
  }
  __syncthreads();
  if (tid < 64) {
    const float* wr = fc3_w + tid * 128;
    float a4[4] = {0.f, 0.f, 0.f, 0.f};
    #pragma unroll 4
    for (int k = 0; k < 128; k += 16) {
      #pragma unroll
      for (int q = 0; q < 4; q++) {
        float4 w = *(const float4*)&wr[k + 4 * q];
        float4 a = *(const float4*)&vecA[k + 4 * q];
        a4[q] += (w.x * a.x + w.y * a.y) + (w.z * a.z + w.w * a.w);
      }
    }
    vecB[tid] = fmaxf(fc3_b[tid] + (a4[0] + a4[1]) + (a4[2] + a4[3]), 0.f);
  }
  __syncthreads();
  {
    const float* wr = fc4_w + tid * 64;
    float a4[4] = {0.f, 0.f, 0.f, 0.f};
    #pragma unroll
    for (int k = 0; k < 64; k += 16) {
      #pragma unroll
      for (int q = 0; q < 4; q++) {
        float4 w = *(const float4*)&wr[k + 4 * q];
        float4 a = *(const float4*)&vecB[k + 4 * q];
        a4[q] += (w.x * a.x + w.y * a.y) + (w.z * a.z + w.w * a.w);
      }
    }
    out[b * 256 + tid] = fc4_b[tid] + (a4[0] + a4[1]) + (a4[2] + a4[3]);
  }
}

extern "C" void kernel_launch(void* const* d_in, const int* in_sizes, int n_in,
                              void* d_out, int out_size, void* d_ws, size_t ws_size,
                              hipStream_t stream) {
  wavenet_kernel<<<BB, NT, 0, stream>>>(
      (const int*)d_in[0],    (const float*)d_in[1],  (const float*)d_in[2],  (const float*)d_in[3],
      (const float*)d_in[4],  (const float*)d_in[5],  (const float*)d_in[6],  (const float*)d_in[7],
      (const float*)d_in[8],  (const float*)d_in[9],  (const float*)d_in[10], (const float*)d_in[11],
      (const float*)d_in[12], (const float*)d_in[13], (const float*)d_in[14], (const float*)d_in[15],
      (const float*)d_in[16], (const float*)d_in[17], (const float*)d_in[18], (const float*)d_in[19],
      (const float*)d_in[20], (const float*)d_in[21], (const float*)d_in[22], (const float*)d_in[23],
      (const float*)d_in[24], (const float*)d_in[25], (float*)d_out);
}

// Round 5
// 203.496 us; speedup vs baseline: 1.0405x; 1.0069x over previous
//
#include <hip/hip_runtime.h>

// WaveNet inference on MFMA. Exploits: (1) only last timestep feeds the FC
// head, (2) skip overwritten each layer (only layer 15's matters),
// (3) receptive field at t=T-1 is 77 steps.
// Round 18 = R16 + audited parts of R17 + SEMANTICS-PROOF permlane:
//  - half-exchanges in the reg path use __builtin_amdgcn_permlane32_swap,
//    runtime-probed (exact 4-point check) into mode 0/1 (either return
//    order) or mode 2 = exact R16 __shfl fallback. Wrong-semantics can
//    only slow down, never corrupt (R17 lesson: raw-asm probe failed).
//  - LDS layers (L0-9): phase3 C-init (16 scalar rb reads) hoisted above
//    phase2's MFMA chain (overlaps; removes a dependent LDS round).
//  - L14 weights pre-staged into pool slot (free after L9) at i=10, L15
//    into bfw[0] at i=13: no staging/barrier after L13; L15 spill->xbuf[0].
//  - rb1w = t+1-shift of assembled rb0w (1 DS round; commutes w/ exchange).
// Regime rules learned (R3/4: >256 thr spills; R8: never trade CUs for
// waves; R9/R11: no serial work to kill barriers; R12: reg plumbing ~ LDS;
// R14: staging off compute waves ~neutral; R15/R16: dependent LDS/DS hops
// on wave 0 are the chain; R17: never ship an unverifiable asm semantic).

#define BB 16
#define TT 8192
#define LL 16
#define W0 77
#define NT 256

typedef __attribute__((ext_vector_type(8)))  short short8;
typedef __attribute__((ext_vector_type(16))) float float16;
typedef __attribute__((ext_vector_type(2)))  unsigned uv2;

#define MFMA_B16(a, b, c) __builtin_amdgcn_mfma_f32_32x32x16_bf16(a, b, c, 0, 0, 0)

__device__ __forceinline__ short f2bs(float f) {   // f32 -> bf16 bits, RNE
  union { float ff; unsigned u; } v; v.ff = f;
  unsigned u = v.u;
  return (short)((u + 0x7FFFu + ((u >> 16) & 1u)) >> 16);
}
__device__ __forceinline__ float b2f(short h) {
  union { unsigned u; float f; } v;
  v.u = ((unsigned)(unsigned short)h) << 16; return v.f;
}
__device__ __forceinline__ unsigned cvtpk(float lo, float hi) {
  unsigned r;
  asm("v_cvt_pk_bf16_f32 %0, %1, %2" : "=v"(r) : "v"(lo), "v"(hi));
  return r;
}
__device__ __forceinline__ short8 mk8(unsigned a, unsigned b, unsigned c, unsigned d) {
  union { unsigned u[4]; short8 s; } z;
  z.u[0] = a; z.u[1] = b; z.u[2] = c; z.u[3] = d; return z.s;
}
__device__ __forceinline__ float u2f(unsigned u) {
  union { unsigned x; float f; } z; z.x = u; return z.f;
}

// D'-words -> B-frag words via cross-half words cr (cr[q] = own[q] from l^32).
// Net transform per pair (A=o[4h+j], C=o[4h+2+j]): A'=[A.lo|C.lo], C'=[A.hi|C.hi].
// Involution. (Validated by R15/R16 passing.)
__device__ __forceinline__ void asmb(const unsigned* own, const unsigned* cr,
                                     int kh, unsigned* o) {
  #pragma unroll
  for (int h = 0; h < 2; h++) {
    o[4*h+0] = kh ? cr[4*h+2] : own[4*h+0];
    o[4*h+1] = kh ? cr[4*h+3] : own[4*h+1];
    o[4*h+2] = kh ? own[4*h+2] : cr[4*h+0];
    o[4*h+3] = kh ? own[4*h+3] : cr[4*h+1];
  }
}

// In-place half-exchange of 8 words. mode 0/1: permlane32_swap builtin
// (either return order); mode 2: __shfl fallback (exact R16 path).
__device__ __forceinline__ void exch(unsigned* o, int kh, int lx32, int mode) {
  if (mode < 2) {
    #pragma unroll
    for (int h = 0; h < 2; h++)
      #pragma unroll
      for (int j = 0; j < 2; j++) {
        unsigned A = o[4*h+j], C = o[4*h+2+j];
        uv2 r = __builtin_amdgcn_permlane32_swap(A, C, false, false);
        o[4*h+j]   = (mode == 0) ? r[0] : r[1];
        o[4*h+2+j] = (mode == 0) ? r[1] : r[0];
      }
  } else {
    unsigned cr[8];
    #pragma unroll
    for (int q = 0; q < 8; q++) cr[q] = (unsigned)__shfl((int)o[q], lx32);
    unsigned t[8];
    asmb(o, cr, kh, t);
    #pragma unroll
    for (int q = 0; q < 8; q++) o[q] = t[q];
  }
}

// A-fragment halves from [row][32] bf16 LDS: A[m][k], k-local=(lane>>5)*8+j.
__device__ __forceinline__ void afrag2(const short* src, int row, int kh, short8* out) {
  out[0] = *(const short8*)&src[row * 32 + 8 * kh];
  out[1] = *(const short8*)&src[row * 32 + 16 + 8 * kh];
}

// load a full row's 8 packed words (B-frag layout) from [row][32] bf16 LDS
__device__ __forceinline__ void ldrow(const short* xb, int row, int kh, unsigned* w8) {
  #pragma unroll
  for (int h = 0; h < 2; h++) {
    short8 v = *(const short8*)&xb[row * 32 + 16 * h + 8 * kh];
    union { short8 s; unsigned u[4]; } z; z.s = v;
    #pragma unroll
    for (int s = 0; s < 4; s++) w8[4 * h + s] = z.u[s];
  }
}

// chunk cid in [0,896): mat=cid>>7, h=(cid>>6)&1, ln=cid&63 -> n=ln&31,k2=ln>>5
// value j: W[16h+8k2+j][n] of matrix mat; dst offset = cid*8 shorts (b128).
__device__ __forceinline__ void load_chunk(
    int li, int cid, float* pf,
    const float* dil_w, const float* filt_w, const float* gate_w, const float* res_w)
{
  int mat = cid >> 7;
  int h = (cid >> 6) & 1, ln = cid & 63;
  int n = ln & 31, k2 = ln >> 5;
  int base = (li * 32 + n) * 32 + 16 * h + 8 * k2;
  if (mat == 6) {
    const float* p = res_w + base;
    #pragma unroll
    for (int j = 0; j < 8; j++) pf[j] = p[j];
  } else {
    const float* w = (mat < 2) ? dil_w : (mat < 4) ? filt_w : gate_w;
    const float* p = w + base * 2 + (mat & 1);
    #pragma unroll
    for (int j = 0; j < 8; j++) pf[j] = p[2 * j];
  }
}

// stage one reg-path layer's frags+bias (staging waves, ptid in [0,192))
__device__ __forceinline__ void stage_layer(
    int li, int ptid, short* dst, float* bdst,
    const float* dil_w, const float* filt_w, const float* gate_w, const float* res_w,
    const float* dil_b, const float* filt_b, const float* gate_b, const float* res_b)
{
  float pf[5][8];
  #pragma unroll
  for (int q = 0; q < 5; q++) {
    int c = ptid + q * 192;
    if (c < 896) load_chunk(li, c, pf[q], dil_w, filt_w, gate_w, res_w);
  }
  #pragma unroll
  for (int q = 0; q < 5; q++) {
    int c = ptid + q * 192;
    if (c < 896) {
      short8 v;
      #pragma unroll
      for (int j = 0; j < 8; j++) v[j] = f2bs(pf[q][j]);
      *(short8*)&dst[c * 8] = v;
    }
  }
  for (int t2 = ptid; t2 < 128; t2 += 192) {
    const float* bsrc = (t2 < 32) ? dil_b : (t2 < 64) ? filt_b : (t2 < 96) ? gate_b : res_b;
    bdst[t2] = bsrc[li * 32 + (t2 & 31)];
  }
}

__global__ __launch_bounds__(NT, 1) void wavenet_kernel(
    const int* __restrict__ tokens,
    const float* __restrict__ emb,
    const float* __restrict__ init_w, const float* __restrict__ init_b,
    const float* __restrict__ dil_w,  const float* __restrict__ dil_b,
    const float* __restrict__ filt_w, const float* __restrict__ filt_b,
    const float* __restrict__ gate_w, const float* __restrict__ gate_b,
    const float* __restrict__ res_w,  const float* __restrict__ res_b,
    const float* __restrict__ skip_w, const float* __restrict__ skip_b,
    const float* __restrict__ end1_w, const float* __restrict__ end1_b,
    const float* __restrict__ end2_w, const float* __restrict__ end2_b,
    const float* __restrict__ fc1_w,  const float* __restrict__ fc1_b,
    const float* __restrict__ fc2_w,  const float* __restrict__ fc2_b,
    const float* __restrict__ fc3_w,  const float* __restrict__ fc3_b,
    const float* __restrict__ fc4_w,  const float* __restrict__ fc4_b,
    float* __restrict__ out)
{
  __shared__ __align__(16) short bfw[2][7168];   // weight frags, double buffer
  __shared__ __align__(16) float bias2[2][128];
  __shared__ __align__(16) short xbuf[2][W0 * 32];  // activation double buffer
  __shared__ __align__(16) short pool[8624];     // emb stage / rb+xm / L14 slot
  __shared__ int tok[W0];
  __shared__ __align__(16) float vecA[256], vecB[256];

  short* rb = pool;          // 76*32 (LDS layers)
  short* xm = pool + 2432;   // 76*32 (LDS layers)
  short* l14w = pool;                      // L14 frag slot (reg path)
  float* l14b = (float*)&pool[7168];       // L14 bias slot (128 f32)

  const int tid  = threadIdx.x;
  const int lane = tid & 63;
  const int wv   = tid >> 6;
  const int m    = lane & 31;
  const int kh   = lane >> 5;
  const int b    = blockIdx.x;

  // ---- tokens ----
  if (tid < W0) tok[tid] = tokens[b * TT + (TT - 1 - tid)];
  __syncthreads();

  // ---- stage emb rows (bf16, rows zero-padded to K=112) ----
  for (int cid = tid; cid < 77 * 14; cid += NT) {
    int u = cid / 14, s = cid % 14;
    const float* er = emb + tok[u] * 100 + s * 8;
    short8 v;
    if (s < 12) {
      #pragma unroll
      for (int j = 0; j < 8; j++) v[j] = f2bs(er[j]);
    } else if (s == 12) {
      #pragma unroll
      for (int j = 0; j < 4; j++) v[j] = f2bs(er[j]);
      #pragma unroll
      for (int j = 4; j < 8; j++) v[j] = 0;
    } else {
      #pragma unroll
      for (int j = 0; j < 8; j++) v[j] = 0;
    }
    *(short8*)&pool[u * 112 + s * 8] = v;
  }
  // stage layer-0 weight frags + biases directly (all threads)
  for (int cid = tid; cid < 896; cid += NT) {
    float pf[8];
    load_chunk(0, cid, pf, dil_w, filt_w, gate_w, res_w);
    short8 v;
    #pragma unroll
    for (int j = 0; j < 8; j++) v[j] = f2bs(pf[j]);
    *(short8*)&bfw[0][cid * 8] = v;
  }
  if (tid < 128) {
    const float* bsrc = (tid < 32) ? dil_b : (tid < 64) ? filt_b : (tid < 96) ? gate_b : res_b;
    bias2[0][tid] = bsrc[tid & 31];
  }
  __syncthreads();

  // ---- init conv (waves 0..2, one 32-row tile each, MFMA over K=112) ----
  if (wv < 3) {
    short8 bi[7];
    #pragma unroll
    for (int s = 0; s < 7; s++) {
      const float* p = init_w + m * 100 + s * 16 + kh * 8;
      short8 v;
      if (s < 6) {
        #pragma unroll
        for (int j = 0; j < 8; j++) v[j] = f2bs(p[j]);
      } else if (kh == 0) {
        #pragma unroll
        for (int j = 0; j < 4; j++) v[j] = f2bs(p[j]);
        #pragma unroll
        for (int j = 4; j < 8; j++) v[j] = 0;
      } else {
        #pragma unroll
        for (int j = 0; j < 8; j++) v[j] = 0;
      }
      bi[s] = v;
    }
    const float binit = init_b[m];
    const int R = wv * 32;
    int u = R + m; if (u > 76) u = 76;
    float16 acc;
    #pragma unroll
    for (int r = 0; r < 16; r++) acc[r] = binit;
    #pragma unroll
    for (int s = 0; s < 7; s++) {
      short8 a = *(const short8*)&pool[u * 112 + s * 16 + kh * 8];
      acc = MFMA_B16(a, bi[s], acc);
    }
    #pragma unroll
    for (int r = 0; r < 16; r++) {
      int row = (r & 3) + 8 * (r >> 2) + 4 * kh;
      int uu = R + row;
      if (uu < W0) xbuf[0][uu * 32 + m] = f2bs(acc[r]);
    }
  }
  __syncthreads();

  // ---- layers 0..9 (LDS pipeline, stride-31 overlapping tiles, 1 barrier) ----
  int Win = W0;
  for (int i = 0; i < 10; i++) {
    const int d = 1 << (i & 3);
    const int Wout = Win - d - 1;
    const int T = (Wout + 31) / 31;
    const short* bw = bfw[i & 1];
    const float* bs = bias2[i & 1];
    const short* xin  = xbuf[i & 1];
    short* xout = xbuf[(i + 1) & 1];

    // -- prefetch scheme A (layers 0-2, T==3): all threads, regs, commit
    float pfo[4][8];
    float pbias = 0.f;
    const int nch = (tid < 128) ? 4 : 3;   // 896 = 3*256 + 128
    const bool oldpf = (T >= 3) && (i + 1 < LL);
    if (oldpf) {
      #pragma unroll
      for (int q = 0; q < 4; q++) {
        if (q < nch)
          load_chunk(i + 1, tid + q * NT, pfo[q], dil_w, filt_w, gate_w, res_w);
      }
      if (tid < 128) {
        const float* bsrc = (tid < 32) ? dil_b : (tid < 64) ? filt_b : (tid < 96) ? gate_b : res_b;
        pbias = bsrc[(i + 1) * 32 + (tid & 31)];
      }
    }
    // -- prefetch scheme B (T==2): waves wv>=T carry the whole staging.
    const bool newpf = (T <= 2) && (i + 1 < LL) && (wv >= T);
    const int nP = NT - T * 64;
    const int ptid = tid - T * 64;
    float pfn[7][8];
    if (newpf) {
      #pragma unroll
      for (int q = 0; q < 7; q++) {
        int c = ptid + q * nP;
        if (c < 896) load_chunk(i + 1, c, pfn[q], dil_w, filt_w, gate_w, res_w);
      }
    }

    if (wv < T) {
      const int R = wv * 31;
      short8 B0[2], B1[2], BW[5][2];
      #pragma unroll
      for (int h = 0; h < 2; h++) {
        B0[h] = *(const short8*)&bw[((0 * 2 + h) * 64 + lane) * 8];
        B1[h] = *(const short8*)&bw[((1 * 2 + h) * 64 + lane) * 8];
      }
      #pragma unroll
      for (int mt = 0; mt < 5; mt++)
        #pragma unroll
        for (int h = 0; h < 2; h++)
          BW[mt][h] = *(const short8*)&bw[(((mt + 2) * 2 + h) * 64 + lane) * 8];

      // ---- phase1: rb rows R..R+31 (boundary row redundant across waves) ----
      int vra = R + m + d; if (vra > Win - 1) vra = Win - 1;
      int vrz = R + m;     if (vrz > Win - 1) vrz = Win - 1;
      short8 aA[2], aZ[2];
      afrag2(xin, vra, kh, aA);
      afrag2(xin, vrz, kh, aZ);
      float16 acc;
      const float bc = bs[m];
      #pragma unroll
      for (int r = 0; r < 16; r++) acc[r] = bc;
      acc = MFMA_B16(aA[0], B0[0], acc);
      acc = MFMA_B16(aA[1], B0[1], acc);
      acc = MFMA_B16(aZ[0], B1[0], acc);
      acc = MFMA_B16(aZ[1], B1[1], acc);
      #pragma unroll
      for (int r = 0; r < 16; r++) {
        int row = (r & 3) + 8 * (r >> 2) + 4 * kh;
        int vr = R + row;
        if (vr <= Wout) rb[vr * 32 + m] = f2bs(acc[r]);
      }
      asm volatile("s_waitcnt lgkmcnt(0)" ::: "memory");  // wave-local P1->P2

      // ---- phase2: f/g convs; also hoist phase3's C-init reads here ----
      const int capA = (R + 31 < Wout) ? (R + 31) : Wout;
      int r1 = R + m + 1; if (r1 > capA) r1 = capA;
      int r0 = R + m;     if (r0 > Wout) r0 = Wout;
      short8 a1[2], a0[2];
      afrag2(rb, r1, kh, a1);
      afrag2(rb, r0, kh, a0);
      float cinit[16];                      // rb[row+1] residual carry (phase3)
      #pragma unroll
      for (int r = 0; r < 16; r++) {
        int row = (r & 3) + 8 * (r >> 2) + 4 * kh;
        int rr = R + row + 1; if (rr > Wout) rr = Wout;
        cinit[r] = b2f(rb[rr * 32 + m]);
      }
      float16 accF, accG;
      const float bf = bs[32 + m], bg = bs[64 + m];
      #pragma unroll
      for (int r = 0; r < 16; r++) { accF[r] = bf; accG[r] = bg; }
      accF = MFMA_B16(a1[0], BW[0][0], accF);
      accF = MFMA_B16(a1[1], BW[0][1], accF);
      accF = MFMA_B16(a0[0], BW[1][0], accF);
      accF = MFMA_B16(a0[1], BW[1][1], accF);
      accG = MFMA_B16(a1[0], BW[2][0], accG);
      accG = MFMA_B16(a1[1], BW[2][1], accG);
      accG = MFMA_B16(a0[0], BW[3][0], accG);
      accG = MFMA_B16(a0[1], BW[3][1], accG);
      #pragma unroll
      for (int r = 0; r < 16; r++) {
        int row = (r & 3) + 8 * (r >> 2) + 4 * kh;
        int uf = R + row;
        if (row < 31 && uf < Wout) {
          float u = __expf(-2.f * accF[r]);
          float v = __expf(-accG[r]);
          float fg = (1.f - u) * __builtin_amdgcn_rcpf((1.f + u) * (1.f + v));
          xm[uf * 32 + m] = f2bs(fg);
        }
      }
      asm volatile("s_waitcnt lgkmcnt(0)" ::: "memory");  // wave-local P2->P3

      // ---- phase3: xnext = rbias + R@xmid + cinit (own-tile xm) ----
      const int capX = (R + 30 < Wout - 1) ? (R + 30) : (Wout - 1);
      int rx = R + m; if (rx > capX) rx = capX;
      short8 aX[2];
      afrag2(xm, rx, kh, aX);
      float16 accX;
      const float br = bs[96 + m];
      #pragma unroll
      for (int r = 0; r < 16; r++) accX[r] = br + cinit[r];
      accX = MFMA_B16(aX[0], BW[4][0], accX);
      accX = MFMA_B16(aX[1], BW[4][1], accX);
      #pragma unroll
      for (int r = 0; r < 16; r++) {
        int row = (r & 3) + 8 * (r >> 2) + 4 * kh;
        int uf = R + row;
        if (row < 31 && uf < Wout) xout[uf * 32 + m] = f2bs(accX[r]);
      }
    } else if (newpf) {
      short* dst = bfw[(i + 1) & 1];
      #pragma unroll
      for (int q = 0; q < 7; q++) {
        int c = ptid + q * nP;
        if (c < 896) {
          short8 v;
          #pragma unroll
          for (int j = 0; j < 8; j++) v[j] = f2bs(pfn[q][j]);
          *(short8*)&dst[c * 8] = v;
        }
      }
      for (int t2 = ptid; t2 < 128; t2 += nP) {
        const float* bsrc = (t2 < 32) ? dil_b : (t2 < 64) ? filt_b : (t2 < 96) ? gate_b : res_b;
        bias2[(i + 1) & 1][t2] = bsrc[(i + 1) * 32 + (t2 & 31)];
      }
    }

    // commit scheme-A frags (layers 0-2 only)
    if (oldpf) {
      short* dst = bfw[(i + 1) & 1];
      #pragma unroll
      for (int q = 0; q < 4; q++) {
        if (q < nch) {
          short8 v;
          #pragma unroll
          for (int j = 0; j < 8; j++) v[j] = f2bs(pfo[q][j]);
          *(short8*)&dst[(tid + q * NT) * 8] = v;
        }
      }
      if (tid < 128) bias2[(i + 1) & 1][tid] = pbias;
    }
    __syncthreads();                        // single barrier per layer
    Win = Wout;
  }

  // ---- layers 10..15: in-register pipeline on wave 0 ----
  // x held as B-frag words xcur[8]: lane l holds X[t=l&31][c=16h+8kh+(0..7)].
  // L10 (Win=34): rows 32,33 stashed in broadcast regs e32/e33.
  {
    const int t31 = lane & 31;
    const int hb  = lane & 32;
    const int lx32 = lane ^ 32;
    unsigned xcur[8], e32[8], e33[8];
    int mode = 2;
    if (wv == 0) {
      const short* xb0 = xbuf[0];          // L9 wrote xbuf[0]
      int tcl = t31 < Win - 1 ? t31 : Win - 1;
      ldrow(xb0, tcl, kh, xcur);
      ldrow(xb0, 32, kh, e32);
      ldrow(xb0, 33, kh, e33);
      // probe permlane32_swap semantics exactly; fallback to shfl otherwise
      {
        unsigned pa = (unsigned)lane;
        unsigned pb = 64u + (unsigned)lane;
        uv2 pr = __builtin_amdgcn_permlane32_swap(pa, pb, false, false);
        unsigned x0  = (unsigned)__shfl((int)pr[0], 0);
        unsigned x32 = (unsigned)__shfl((int)pr[0], 32);
        unsigned y0  = (unsigned)__shfl((int)pr[1], 0);
        unsigned y32 = (unsigned)__shfl((int)pr[1], 32);
        // want A'=[A.lo|C.lo] (lane0=0, lane32=64), C'=[A.hi|C.hi] (32, 96)
        if      (x0 == 0u  && x32 == 64u && y0 == 32u && y32 == 96u) mode = 0;
        else if (y0 == 0u  && y32 == 64u && x0 == 32u && x32 == 96u) mode = 1;
      }
    }

    #pragma unroll
    for (int i = 10; i < LL; i++) {
      const int d = 1 << (i & 3);
      const int Wout = Win - d - 1;
      // slot map: 10->bfw[0],11->bfw[1],12->bfw[0],13->bfw[1],14->pool,15->bfw[0]
      const short* bw = (i == 14) ? l14w : (i == 15) ? bfw[0] : bfw[i & 1];
      const float* bs = (i == 14) ? l14b : (i == 15) ? bias2[0] : bias2[i & 1];

      if (wv >= 1) {
        const int ptid = tid - 64;
        if (i == 10) {
          // dual-stage: interleave loads of L11 and L14, then write both
          float pfA[5][8], pfB[5][8];
          #pragma unroll
          for (int q = 0; q < 5; q++) {
            int c = ptid + q * 192;
            if (c < 896) load_chunk(11, c, pfA[q], dil_w, filt_w, gate_w, res_w);
          }
          #pragma unroll
          for (int q = 0; q < 5; q++) {
            int c = ptid + q * 192;
            if (c < 896) load_chunk(14, c, pfB[q], dil_w, filt_w, gate_w, res_w);
          }
          #pragma unroll
          for (int q = 0; q < 5; q++) {
            int c = ptid + q * 192;
            if (c < 896) {
              short8 vA, vB;
              #pragma unroll
              for (int j = 0; j < 8; j++) { vA[j] = f2bs(pfA[q][j]); vB[j] = f2bs(pfB[q][j]); }
              *(short8*)&bfw[1][c * 8] = vA;
              *(short8*)&l14w[c * 8]   = vB;
            }
          }
          for (int t2 = ptid; t2 < 128; t2 += 192) {
            const float* bsrc = (t2 < 32) ? dil_b : (t2 < 64) ? filt_b : (t2 < 96) ? gate_b : res_b;
            bias2[1][t2] = bsrc[11 * 32 + (t2 & 31)];
            l14b[t2]     = bsrc[14 * 32 + (t2 & 31)];
          }
        } else if (i == 11) {
          stage_layer(12, ptid, bfw[0], bias2[0], dil_w, filt_w, gate_w, res_w,
                      dil_b, filt_b, gate_b, res_b);
        } else if (i == 12) {
          stage_layer(13, ptid, bfw[1], bias2[1], dil_w, filt_w, gate_w, res_w,
                      dil_b, filt_b, gate_b, res_b);
        } else if (i == 13) {
          stage_layer(15, ptid, bfw[0], bias2[0], dil_w, filt_w, gate_w, res_w,
                      dil_b, filt_b, gate_b, res_b);
        }
      }

      if (wv == 0) {
        // weight A-frags (same LDS indices as old-path B-frags)
        short8 WA[7][2];
        #pragma unroll
        for (int mt = 0; mt < 7; mt++)
          #pragma unroll
          for (int h = 0; h < 2; h++)
            WA[mt][h] = *(const short8*)&bw[((mt * 2 + h) * 64 + lane) * 8];

        // ---- phase1: residual = db + W1.x[t] + W0.x[t+d] (xcur-first order
        //      hides the xd DS round under two MFMAs) ----
        unsigned xd[8];
        if (i == 10) {
          int td = t31 + d;                 // d=4: lanes 28..31 -> 32..35
          int ts = td > 31 ? 31 : td;
          #pragma unroll
          for (int q = 0; q < 8; q++) {
            unsigned s = (unsigned)__shfl((int)xcur[q], hb | ts);
            s = (td == 32) ? e32[q] : s;
            s = (td >= 33) ? e33[q] : s;    // clamp Win-1 = 33
            xd[q] = s;
          }
        } else {
          int td = t31 + d; if (td > Win - 1) td = Win - 1;
          int srcd = hb | td;
          #pragma unroll
          for (int q = 0; q < 8; q++) xd[q] = (unsigned)__shfl((int)xcur[q], srcd);
        }
        float16 acc;
        #pragma unroll
        for (int g = 0; g < 4; g++) {
          float4 b4 = *(const float4*)&bs[4 * kh + 8 * g];
          acc[4*g+0] = b4.x; acc[4*g+1] = b4.y; acc[4*g+2] = b4.z; acc[4*g+3] = b4.w;
        }
        acc = MFMA_B16(WA[1][0], mk8(xcur[0], xcur[1], xcur[2], xcur[3]), acc);
        acc = MFMA_B16(WA[1][1], mk8(xcur[4], xcur[5], xcur[6], xcur[7]), acc);
        acc = MFMA_B16(WA[0][0], mk8(xd[0], xd[1], xd[2], xd[3]), acc);
        acc = MFMA_B16(WA[0][1], mk8(xd[4], xd[5], xd[6], xd[7]), acc);

        // assemble rb0w (exchange) then rb1w = t+1 shift (one DS round)
        unsigned rb0w[8];
        #pragma unroll
        for (int q = 0; q < 8; q++) rb0w[q] = cvtpk(acc[2 * q], acc[2 * q + 1]);
        exch(rb0w, kh, lx32, mode);
        int t1 = t31 + 1; if (t1 > Wout) t1 = Wout;
        int s1o = hb | t1;
        unsigned rb1w[8];
        #pragma unroll
        for (int q = 0; q < 8; q++) rb1w[q] = (unsigned)__shfl((int)rb0w[q], s1o);

        // ---- phase2: f/g convs (rb0-first order hides the shift round) ----
        float16 accF, accG;
        #pragma unroll
        for (int g = 0; g < 4; g++) {
          float4 bF = *(const float4*)&bs[32 + 4 * kh + 8 * g];
          float4 bG = *(const float4*)&bs[64 + 4 * kh + 8 * g];
          accF[4*g+0] = bF.x; accF[4*g+1] = bF.y; accF[4*g+2] = bF.z; accF[4*g+3] = bF.w;
          accG[4*g+0] = bG.x; accG[4*g+1] = bG.y; accG[4*g+2] = bG.z; accG[4*g+3] = bG.w;
        }
        short8 RB00 = mk8(rb0w[0], rb0w[1], rb0w[2], rb0w[3]);
        short8 RB01 = mk8(rb0w[4], rb0w[5], rb0w[6], rb0w[7]);
        short8 RB10 = mk8(rb1w[0], rb1w[1], rb1w[2], rb1w[3]);
        short8 RB11 = mk8(rb1w[4], rb1w[5], rb1w[6], rb1w[7]);
        accF = MFMA_B16(WA[3][0], RB00, accF);
        accF = MFMA_B16(WA[3][1], RB01, accF);
        accF = MFMA_B16(WA[2][0], RB10, accF);
        accF = MFMA_B16(WA[2][1], RB11, accF);
        accG = MFMA_B16(WA[5][0], RB00, accG);
        accG = MFMA_B16(WA[5][1], RB01, accG);
        accG = MFMA_B16(WA[4][0], RB10, accG);
        accG = MFMA_B16(WA[4][1], RB11, accG);
        float fg[16];
        #pragma unroll
        for (int r = 0; r < 16; r++) {
          float u = __expf(-2.f * accF[r]);
          float v = __expf(-accG[r]);
          fg[r] = (1.f - u) * __builtin_amdgcn_rcpf((1.f + u) * (1.f + v));
        }
        unsigned wxm[8];
        #pragma unroll
        for (int q = 0; q < 8; q++) wxm[q] = cvtpk(fg[2 * q], fg[2 * q + 1]);

        if (i == LL - 1) {
          // spill gated row 0 (t=0 in lanes 0/32) to xbuf[0] for the tail
          if (t31 == 0) {
            #pragma unroll
            for (int q = 0; q < 8; q++) {
              int c0 = (2 * q & 3) + 8 * (q >> 1) + 4 * kh;
              *(unsigned*)&xbuf[0][c0] = wxm[q];
            }
          }
        } else {
          // ---- phase3: xnext = rbias + Wr.xm + residual[t+1] ----
          unsigned x1[8];                    // D'-layout shifted residual
          #pragma unroll
          for (int q = 0; q < 8; q++) x1[q] = rb1w[q];
          exch(x1, kh, lx32, mode);          // involution: back to D' layout
          unsigned xmw[8];
          #pragma unroll
          for (int q = 0; q < 8; q++) xmw[q] = wxm[q];
          exch(xmw, kh, lx32, mode);
          float16 accX;
          #pragma unroll
          for (int g = 0; g < 4; g++) {
            float4 bR = *(const float4*)&bs[96 + 4 * kh + 8 * g];
            #pragma unroll
            for (int j = 0; j < 4; j++) {
              int r = 4 * g + j;
              unsigned w = x1[r >> 1];
              float rv = (r & 1) ? u2f(w & 0xFFFF0000u) : u2f(w << 16);
              accX[r] = ((const float*)&bR)[j] + rv;
            }
          }
          accX = MFMA_B16(WA[6][0], mk8(xmw[0], xmw[1], xmw[2], xmw[3]), accX);
          accX = MFMA_B16(WA[6][1], mk8(xmw[4], xmw[5], xmw[6], xmw[7]), accX);
          #pragma unroll
          for (int q = 0; q < 8; q++) xcur[q] = cvtpk(accX[2 * q], accX[2 * q + 1]);
          exch(xcur, kh, lx32, mode);
        }
      }
      if (i <= 13) __syncthreads();
      Win = Wout;
    }
  }
  __syncthreads();   // xbuf[0] spill handoff to all waves

  // ---- tail (f32 VALU, 4 waves): skip(l15) -> end1 -> end2 -> fc1..fc4 ----
  {
    const short* xmt = xbuf[0];
    float acc = skip_b[15 * 256 + tid];
    const float* wr = skip_w + (15 * 256 + tid) * 32;
    #pragma unroll
    for (int k = 0; k < 32; k += 4) {
      float4 w = *(const float4*)&wr[k];
      acc += (w.x * b2f(xmt[k]) + w.y * b2f(xmt[k+1])) + (w.z * b2f(xmt[k+2]) + w.w * b2f(xmt[k+3]));
    }
    vecA[tid] = fmaxf(acc, 0.f);
  }
  __syncthreads();
  {
    const float* wr = end1_w + tid * 256;
    float a4[4] = {0.f, 0.f, 0.f, 0.f};
    #pragma unroll 8
    for (int k = 0; k < 256; k += 16) {
      #pragma unroll
      for (int q = 0; q < 4; q++) {
        float4 w = *(const float4*)&wr[k + 4 * q];
        float4 a = *(const float4*)&vecA[k + 4 * q];
        a4[q] += (w.x * a.x + w.y * a.y) + (w.z * a.z + w.w * a.w);
      }
    }
    vecB[tid] = fmaxf(end1_b[tid] + (a4[0] + a4[1]) + (a4[2] + a4[3]), 0.f);
  }
  __syncthreads();
  {
    const float* wr = end2_w + tid * 256;
    float a4[4] = {0.f, 0.f, 0.f, 0.f};
    #pragma unroll 8
    for (int k = 0; k < 256; k += 16) {
      #pragma unroll
      for (int q = 0; q < 4; q++) {
        float4 w = *(const float4*)&wr[k + 4 * q];
        float4 a = *(const float4*)&vecB[k + 4 * q];
        a4[q] += (w.x * a.x + w.y * a.y) + (w.z * a.z + w.w * a.w);
      }
    }
    float h2 = end2_b[tid] + (a4[0] + a4[1]) + (a4[2] + a4[3]);
    vecA[tid] = h2;   // safe: vecA readers (end1) all past the last barrier
  }
  __syncthreads();
  if (tid < 128) {
    const float* wr = fc1_w + tid * 256;
    float a4[4] = {0.f, 0.f, 0.f, 0.f};
    #pragma unroll 8
    for (int k = 0; k < 256; k += 16) {
      #pragma unroll
      for (int q = 0; q < 4; q++) {
        float4 w = *(const float4*)&wr[k + 4 * q];
        float4 a = *(const float4*)&vecA[k + 4 * q];
        a4[q] += (w.x * a.x + w.y * a.y) + (w.z * a.z + w.w * a.w);
      }
    }
    vecB[tid] = fmaxf(fc1_b[tid] + (a4[0] + a4[1]) + (a4[2] + a4[3]), 0.f);
  }
  __syncthreads();
  if (tid < 128) {
    const float* wr = fc2_w + tid * 128;
    float a4[4] = {0.f, 0.f, 0.f, 0.f};
    #pragma unroll 4
    for (int k = 0; k < 128; k += 16) {
      #pragma unroll
      for (int q = 0; q < 4; q++) {
        float4 w = *(const float4*)&wr[k + 4 * q];
        float4 a = *(const float4*)&vecB[k + 4 * q];
        a4[q] += (w.x * a.x + w.y * a.y) + (w.z * a.z + w.w * a.w);
      }
    }
    vecA[tid] = fmaxf(fc2_b[tid] + (a4[0] + a4[1]) + (a4[2] + a4[3]), 0.f);
  }
  __syncthreads();
  if (tid < 64) {
    const float* wr = fc3_w + tid * 128;
    float a4[4] = {0.f, 0.f, 0.f, 0.f};
    #pragma unroll 4
    for (int k = 0; k < 128; k += 16) {
      #pragma unroll
      for (int q = 0; q < 4; q++) {
        float4 w = *(const float4*)&wr[k + 4 * q];
        float4 a = *(const float4*)&vecA[k + 4 * q];
        a4[q] += (w.x * a.x + w.y * a.y) + (w.z * a.z + w.w * a.w);
      }
    }
    vecB[tid] = fmaxf(fc3_b[tid] + (a4[0] + a4[1]) + (a4[2] + a4[3]), 0.f);
  }
  __syncthreads();
  {
    const float* wr = fc4_w + tid * 64;
    float a4[4] = {0.f, 0.f, 0.f, 0.f};
    #pragma unroll
    for (int k = 0; k < 64; k += 16) {
      #pragma unroll
      for (int q = 0; q < 4; q++) {
        float4 w = *(const float4*)&wr[k + 4 * q];
        float4 a = *(const float4*)&vecB[k + 4 * q];
        a4[q] += (w.x * a.x + w.y * a.y) + (w.z * a.z + w.w * a.w);
      }
    }
    out[b * 256 + tid] = fc4_b[tid] + (a4[0] + a4[1]) + (a4[2] + a4[3]);
  }
}

extern "C" void kernel_launch(void* const* d_in, const int* in_sizes, int n_in,
                              void* d_out, int out_size, void* d_ws, size_t ws_size,
                              hipStream_t stream) {
  wavenet_kernel<<<BB, NT, 0, stream>>>(
      (const int*)d_in[0],    (const float*)d_in[1],  (const float*)d_in[2],  (const float*)d_in[3],
      (const float*)d_in[4],  (const float*)d_in[5],  (const float*)d_in[6],  (const float*)d_in[7],
      (const float*)d_in[8],  (const float*)d_in[9],  (const float*)d_in[10], (const float*)d_in[11],
      (const float*)d_in[12], (const float*)d_in[13], (const float*)d_in[14], (const float*)d_in[15],
      (const float*)d_in[16], (const float*)d_in[17], (const float*)d_in[18], (const float*)d_in[19],
      (const float*)d_in[20], (const float*)d_in[21], (const float*)d_in[22], (const float*)d_in[23],
      (const float*)d_in[24], (const float*)d_in[25], (float*)d_out);
}

// Round 6
// 193.551 us; speedup vs baseline: 1.0939x; 1.0514x over previous
//
#include <hip/hip_runtime.h>

// WaveNet inference on MFMA. Exploits: (1) only last timestep feeds the FC
// head, (2) skip overwritten each layer (only layer 15's matters),
// (3) receptive field at t=T-1 is 77 steps.
// Round 19 = R18 +
//  - TAIL REDESIGN (primary): the 6 matvec stages were per-thread-row reads
//    (64 cache lines per wave load -> TA-bound). Now split-K: thread
//    (rb=tid>>4, s=tid&15) reads 16B-interleaved k-slices => 16 lines/load,
//    all 256 threads active every stage; per-row partials live in 16
//    consecutive lanes -> 4x shfl_xor reduce, no LDS, same barrier count.
//  - MFMA chain splits (secondary): 4-deep chains -> 2+2 independent accs
//    in both layer paths (merge at output); init conv 7 -> 4+3.
// Regime rules learned (R3/4: >256 thr spills; R8: never trade CUs for
// waves; R9/R11: no serial work to kill barriers; R12: reg plumbing ~ LDS;
// R14: staging off compute waves ~neutral; R15/R16: dependent hops on the
// critical wave ~400-800cy each; R17: never ship unverifiable asm;
// R15-18 totals imply effective clock ~0.5-1GHz and a ~50us unexplained
// block => tail uncoalesced loads are the prime suspect this round).

#define BB 16
#define TT 8192
#define LL 16
#define W0 77
#define NT 256

typedef __attribute__((ext_vector_type(8)))  short short8;
typedef __attribute__((ext_vector_type(16))) float float16;
typedef __attribute__((ext_vector_type(2)))  unsigned uv2;

#define MFMA_B16(a, b, c) __builtin_amdgcn_mfma_f32_32x32x16_bf16(a, b, c, 0, 0, 0)

__device__ __forceinline__ short f2bs(float f) {   // f32 -> bf16 bits, RNE
  union { float ff; unsigned u; } v; v.ff = f;
  unsigned u = v.u;
  return (short)((u + 0x7FFFu + ((u >> 16) & 1u)) >> 16);
}
__device__ __forceinline__ float b2f(short h) {
  union { unsigned u; float f; } v;
  v.u = ((unsigned)(unsigned short)h) << 16; return v.f;
}
__device__ __forceinline__ unsigned cvtpk(float lo, float hi) {
  unsigned r;
  asm("v_cvt_pk_bf16_f32 %0, %1, %2" : "=v"(r) : "v"(lo), "v"(hi));
  return r;
}
__device__ __forceinline__ short8 mk8(unsigned a, unsigned b, unsigned c, unsigned d) {
  union { unsigned u[4]; short8 s; } z;
  z.u[0] = a; z.u[1] = b; z.u[2] = c; z.u[3] = d; return z.s;
}
__device__ __forceinline__ float u2f(unsigned u) {
  union { unsigned x; float f; } z; z.x = u; return z.f;
}

// D'-words -> B-frag words via cross-half words cr (cr[q] = own[q] from l^32).
__device__ __forceinline__ void asmb(const unsigned* own, const unsigned* cr,
                                     int kh, unsigned* o) {
  #pragma unroll
  for (int h = 0; h < 2; h++) {
    o[4*h+0] = kh ? cr[4*h+2] : own[4*h+0];
    o[4*h+1] = kh ? cr[4*h+3] : own[4*h+1];
    o[4*h+2] = kh ? own[4*h+2] : cr[4*h+0];
    o[4*h+3] = kh ? own[4*h+3] : cr[4*h+1];
  }
}

// In-place half-exchange of 8 words. mode 0/1: permlane32_swap builtin
// (either return order); mode 2: __shfl fallback (exact R16 path).
__device__ __forceinline__ void exch(unsigned* o, int kh, int lx32, int mode) {
  if (mode < 2) {
    #pragma unroll
    for (int h = 0; h < 2; h++)
      #pragma unroll
      for (int j = 0; j < 2; j++) {
        unsigned A = o[4*h+j], C = o[4*h+2+j];
        uv2 r = __builtin_amdgcn_permlane32_swap(A, C, false, false);
        o[4*h+j]   = (mode == 0) ? r[0] : r[1];
        o[4*h+2+j] = (mode == 0) ? r[1] : r[0];
      }
  } else {
    unsigned cr[8];
    #pragma unroll
    for (int q = 0; q < 8; q++) cr[q] = (unsigned)__shfl((int)o[q], lx32);
    unsigned t[8];
    asmb(o, cr, kh, t);
    #pragma unroll
    for (int q = 0; q < 8; q++) o[q] = t[q];
  }
}

// A-fragment halves from [row][32] bf16 LDS: A[m][k], k-local=(lane>>5)*8+j.
__device__ __forceinline__ void afrag2(const short* src, int row, int kh, short8* out) {
  out[0] = *(const short8*)&src[row * 32 + 8 * kh];
  out[1] = *(const short8*)&src[row * 32 + 16 + 8 * kh];
}

// load a full row's 8 packed words (B-frag layout) from [row][32] bf16 LDS
__device__ __forceinline__ void ldrow(const short* xb, int row, int kh, unsigned* w8) {
  #pragma unroll
  for (int h = 0; h < 2; h++) {
    short8 v = *(const short8*)&xb[row * 32 + 16 * h + 8 * kh];
    union { short8 s; unsigned u[4]; } z; z.s = v;
    #pragma unroll
    for (int s = 0; s < 4; s++) w8[4 * h + s] = z.u[s];
  }
}

// chunk cid in [0,896): mat=cid>>7, h=(cid>>6)&1, ln=cid&63 -> n=ln&31,k2=ln>>5
__device__ __forceinline__ void load_chunk(
    int li, int cid, float* pf,
    const float* dil_w, const float* filt_w, const float* gate_w, const float* res_w)
{
  int mat = cid >> 7;
  int h = (cid >> 6) & 1, ln = cid & 63;
  int n = ln & 31, k2 = ln >> 5;
  int base = (li * 32 + n) * 32 + 16 * h + 8 * k2;
  if (mat == 6) {
    const float* p = res_w + base;
    #pragma unroll
    for (int j = 0; j < 8; j++) pf[j] = p[j];
  } else {
    const float* w = (mat < 2) ? dil_w : (mat < 4) ? filt_w : gate_w;
    const float* p = w + base * 2 + (mat & 1);
    #pragma unroll
    for (int j = 0; j < 8; j++) pf[j] = p[2 * j];
  }
}

// stage one reg-path layer's frags+bias (staging waves, ptid in [0,192))
__device__ __forceinline__ void stage_layer(
    int li, int ptid, short* dst, float* bdst,
    const float* dil_w, const float* filt_w, const float* gate_w, const float* res_w,
    const float* dil_b, const float* filt_b, const float* gate_b, const float* res_b)
{
  float pf[5][8];
  #pragma unroll
  for (int q = 0; q < 5; q++) {
    int c = ptid + q * 192;
    if (c < 896) load_chunk(li, c, pf[q], dil_w, filt_w, gate_w, res_w);
  }
  #pragma unroll
  for (int q = 0; q < 5; q++) {
    int c = ptid + q * 192;
    if (c < 896) {
      short8 v;
      #pragma unroll
      for (int j = 0; j < 8; j++) v[j] = f2bs(pf[q][j]);
      *(short8*)&dst[c * 8] = v;
    }
  }
  for (int t2 = ptid; t2 < 128; t2 += 192) {
    const float* bsrc = (t2 < 32) ? dil_b : (t2 < 64) ? filt_b : (t2 < 96) ? gate_b : res_b;
    bdst[t2] = bsrc[li * 32 + (t2 & 31)];
  }
}

// Coalesced split-K matvec stage: W[R][K] row-major, vin LDS f32[K],
// vout f32[R] (LDS or global). Thread (rb=tid>>4, s=tid&15) reads
// 16B-interleaved k-slices (wave load = 16 cache lines, not 64); the 16
// per-row partials sit in 16 consecutive lanes -> shfl_xor reduce; thread
// (rb,s) writes row rb+16s (cndmask select chain; no runtime indexing).
template<int R, int K, bool RELU>
__device__ __forceinline__ void mv_stage(const float* __restrict__ W,
                                         const float* __restrict__ bias,
                                         const float* vin, float* vout, int tid)
{
  constexpr int J = K >> 6;                 // float4 groups per pass
  constexpr int P = R >> 4;                 // passes (rows/16)
  const int s = tid & 15, rb = tid >> 4;
  float4 vf[J];
  #pragma unroll
  for (int j = 0; j < J; j++) vf[j] = *(const float4*)&vin[(s + 16 * j) * 4];
  float part[P];
  #pragma unroll
  for (int p = 0; p < P; p++) {
    const float* wr = W + (rb + 16 * p) * K;
    float a = 0.f, c = 0.f;
    #pragma unroll
    for (int j = 0; j < J; j++) {
      float4 w = *(const float4*)&wr[(s + 16 * j) * 4];
      a += w.x * vf[j].x + w.y * vf[j].y;
      c += w.z * vf[j].z + w.w * vf[j].w;
    }
    part[p] = a + c;
  }
  #pragma unroll
  for (int p = 0; p < P; p++)
    #pragma unroll
    for (int d2 = 1; d2 < 16; d2 <<= 1)
      part[p] += __shfl_xor(part[p], d2);
  if (s < P) {
    float val = part[0];
    #pragma unroll
    for (int p = 1; p < P; p++) val = (s == p) ? part[p] : val;
    int ro = rb + 16 * s;
    float r2 = val + bias[ro];
    if (RELU) r2 = fmaxf(r2, 0.f);
    vout[ro] = r2;
  }
}

__global__ __launch_bounds__(NT, 1) void wavenet_kernel(
    const int* __restrict__ tokens,
    const float* __restrict__ emb,
    const float* __restrict__ init_w, const float* __restrict__ init_b,
    const float* __restrict__ dil_w,  const float* __restrict__ dil_b,
    const float* __restrict__ filt_w, const float* __restrict__ filt_b,
    const float* __restrict__ gate_w, const float* __restrict__ gate_b,
    const float* __restrict__ res_w,  const float* __restrict__ res_b,
    const float* __restrict__ skip_w, const float* __restrict__ skip_b,
    const float* __restrict__ end1_w, const float* __restrict__ end1_b,
    const float* __restrict__ end2_w, const float* __restrict__ end2_b,
    const float* __restrict__ fc1_w,  const float* __restrict__ fc1_b,
    const float* __restrict__ fc2_w,  const float* __restrict__ fc2_b,
    const float* __restrict__ fc3_w,  const float* __restrict__ fc3_b,
    const float* __restrict__ fc4_w,  const float* __restrict__ fc4_b,
    float* __restrict__ out)
{
  __shared__ __align__(16) short bfw[2][7168];   // weight frags, double buffer
  __shared__ __align__(16) float bias2[2][128];
  __shared__ __align__(16) short xbuf[2][W0 * 32];  // activation double buffer
  __shared__ __align__(16) short pool[8624];     // emb stage / rb+xm / L14 slot
  __shared__ int tok[W0];
  __shared__ __align__(16) float vecA[256], vecB[256];

  short* rb = pool;          // 76*32 (LDS layers)
  short* xm = pool + 2432;   // 76*32 (LDS layers)
  short* l14w = pool;                      // L14 frag slot (reg path)
  float* l14b = (float*)&pool[7168];       // L14 bias slot (128 f32)

  const int tid  = threadIdx.x;
  const int lane = tid & 63;
  const int wv   = tid >> 6;
  const int m    = lane & 31;
  const int kh   = lane >> 5;
  const int b    = blockIdx.x;

  // ---- tokens ----
  if (tid < W0) tok[tid] = tokens[b * TT + (TT - 1 - tid)];
  __syncthreads();

  // ---- stage emb rows (bf16, rows zero-padded to K=112) ----
  for (int cid = tid; cid < 77 * 14; cid += NT) {
    int u = cid / 14, s = cid % 14;
    const float* er = emb + tok[u] * 100 + s * 8;
    short8 v;
    if (s < 12) {
      #pragma unroll
      for (int j = 0; j < 8; j++) v[j] = f2bs(er[j]);
    } else if (s == 12) {
      #pragma unroll
      for (int j = 0; j < 4; j++) v[j] = f2bs(er[j]);
      #pragma unroll
      for (int j = 4; j < 8; j++) v[j] = 0;
    } else {
      #pragma unroll
      for (int j = 0; j < 8; j++) v[j] = 0;
    }
    *(short8*)&pool[u * 112 + s * 8] = v;
  }
  // stage layer-0 weight frags + biases directly (all threads)
  for (int cid = tid; cid < 896; cid += NT) {
    float pf[8];
    load_chunk(0, cid, pf, dil_w, filt_w, gate_w, res_w);
    short8 v;
    #pragma unroll
    for (int j = 0; j < 8; j++) v[j] = f2bs(pf[j]);
    *(short8*)&bfw[0][cid * 8] = v;
  }
  if (tid < 128) {
    const float* bsrc = (tid < 32) ? dil_b : (tid < 64) ? filt_b : (tid < 96) ? gate_b : res_b;
    bias2[0][tid] = bsrc[tid & 31];
  }
  __syncthreads();

  // ---- init conv (waves 0..2, one 32-row tile each, MFMA K=112, 4+3 split) ----
  if (wv < 3) {
    short8 bi[7];
    #pragma unroll
    for (int s = 0; s < 7; s++) {
      const float* p = init_w + m * 100 + s * 16 + kh * 8;
      short8 v;
      if (s < 6) {
        #pragma unroll
        for (int j = 0; j < 8; j++) v[j] = f2bs(p[j]);
      } else if (kh == 0) {
        #pragma unroll
        for (int j = 0; j < 4; j++) v[j] = f2bs(p[j]);
        #pragma unroll
        for (int j = 4; j < 8; j++) v[j] = 0;
      } else {
        #pragma unroll
        for (int j = 0; j < 8; j++) v[j] = 0;
      }
      bi[s] = v;
    }
    const float binit = init_b[m];
    const int R = wv * 32;
    int u = R + m; if (u > 76) u = 76;
    float16 accA, accB;
    #pragma unroll
    for (int r = 0; r < 16; r++) { accA[r] = binit; accB[r] = 0.f; }
    #pragma unroll
    for (int s = 0; s < 7; s++) {
      short8 a = *(const short8*)&pool[u * 112 + s * 16 + kh * 8];
      if (s < 4) accA = MFMA_B16(a, bi[s], accA);
      else       accB = MFMA_B16(a, bi[s], accB);
    }
    #pragma unroll
    for (int r = 0; r < 16; r++) {
      int row = (r & 3) + 8 * (r >> 2) + 4 * kh;
      int uu = R + row;
      if (uu < W0) xbuf[0][uu * 32 + m] = f2bs(accA[r] + accB[r]);
    }
  }
  __syncthreads();

  // ---- layers 0..9 (LDS pipeline, stride-31 overlapping tiles, 1 barrier) ----
  int Win = W0;
  for (int i = 0; i < 10; i++) {
    const int d = 1 << (i & 3);
    const int Wout = Win - d - 1;
    const int T = (Wout + 31) / 31;
    const short* bw = bfw[i & 1];
    const float* bs = bias2[i & 1];
    const short* xin  = xbuf[i & 1];
    short* xout = xbuf[(i + 1) & 1];

    float pfo[4][8];
    float pbias = 0.f;
    const int nch = (tid < 128) ? 4 : 3;   // 896 = 3*256 + 128
    const bool oldpf = (T >= 3) && (i + 1 < LL);
    if (oldpf) {
      #pragma unroll
      for (int q = 0; q < 4; q++) {
        if (q < nch)
          load_chunk(i + 1, tid + q * NT, pfo[q], dil_w, filt_w, gate_w, res_w);
      }
      if (tid < 128) {
        const float* bsrc = (tid < 32) ? dil_b : (tid < 64) ? filt_b : (tid < 96) ? gate_b : res_b;
        pbias = bsrc[(i + 1) * 32 + (tid & 31)];
      }
    }
    const bool newpf = (T <= 2) && (i + 1 < LL) && (wv >= T);
    const int nP = NT - T * 64;
    const int ptid = tid - T * 64;
    float pfn[7][8];
    if (newpf) {
      #pragma unroll
      for (int q = 0; q < 7; q++) {
        int c = ptid + q * nP;
        if (c < 896) load_chunk(i + 1, c, pfn[q], dil_w, filt_w, gate_w, res_w);
      }
    }

    if (wv < T) {
      const int R = wv * 31;
      short8 B0[2], B1[2], BW[5][2];
      #pragma unroll
      for (int h = 0; h < 2; h++) {
        B0[h] = *(const short8*)&bw[((0 * 2 + h) * 64 + lane) * 8];
        B1[h] = *(const short8*)&bw[((1 * 2 + h) * 64 + lane) * 8];
      }
      #pragma unroll
      for (int mt = 0; mt < 5; mt++)
        #pragma unroll
        for (int h = 0; h < 2; h++)
          BW[mt][h] = *(const short8*)&bw[(((mt + 2) * 2 + h) * 64 + lane) * 8];

      // ---- phase1: rb rows R..R+31 (2+2 split chains) ----
      int vra = R + m + d; if (vra > Win - 1) vra = Win - 1;
      int vrz = R + m;     if (vrz > Win - 1) vrz = Win - 1;
      short8 aA[2], aZ[2];
      afrag2(xin, vra, kh, aA);
      afrag2(xin, vrz, kh, aZ);
      float16 p1a, p1b;
      const float bc = bs[m];
      #pragma unroll
      for (int r = 0; r < 16; r++) { p1a[r] = bc; p1b[r] = 0.f; }
      p1a = MFMA_B16(aA[0], B0[0], p1a);
      p1a = MFMA_B16(aA[1], B0[1], p1a);
      p1b = MFMA_B16(aZ[0], B1[0], p1b);
      p1b = MFMA_B16(aZ[1], B1[1], p1b);
      #pragma unroll
      for (int r = 0; r < 16; r++) {
        int row = (r & 3) + 8 * (r >> 2) + 4 * kh;
        int vr = R + row;
        if (vr <= Wout) rb[vr * 32 + m] = f2bs(p1a[r] + p1b[r]);
      }
      asm volatile("s_waitcnt lgkmcnt(0)" ::: "memory");  // wave-local P1->P2

      // ---- phase2: f/g convs (2+2 splits); hoisted phase3 C-init ----
      const int capA = (R + 31 < Wout) ? (R + 31) : Wout;
      int r1 = R + m + 1; if (r1 > capA) r1 = capA;
      int r0 = R + m;     if (r0 > Wout) r0 = Wout;
      short8 a1[2], a0[2];
      afrag2(rb, r1, kh, a1);
      afrag2(rb, r0, kh, a0);
      float cinit[16];                      // rb[row+1] residual carry (phase3)
      #pragma unroll
      for (int r = 0; r < 16; r++) {
        int row = (r & 3) + 8 * (r >> 2) + 4 * kh;
        int rr = R + row + 1; if (rr > Wout) rr = Wout;
        cinit[r] = b2f(rb[rr * 32 + m]);
      }
      float16 Fa, Fb, Ga, Gb;
      const float bf = bs[32 + m], bg = bs[64 + m];
      #pragma unroll
      for (int r = 0; r < 16; r++) { Fa[r] = bf; Fb[r] = 0.f; Ga[r] = bg; Gb[r] = 0.f; }
      Fa = MFMA_B16(a1[0], BW[0][0], Fa);
      Fa = MFMA_B16(a1[1], BW[0][1], Fa);
      Fb = MFMA_B16(a0[0], BW[1][0], Fb);
      Fb = MFMA_B16(a0[1], BW[1][1], Fb);
      Ga = MFMA_B16(a1[0], BW[2][0], Ga);
      Ga = MFMA_B16(a1[1], BW[2][1], Ga);
      Gb = MFMA_B16(a0[0], BW[3][0], Gb);
      Gb = MFMA_B16(a0[1], BW[3][1], Gb);
      #pragma unroll
      for (int r = 0; r < 16; r++) {
        int row = (r & 3) + 8 * (r >> 2) + 4 * kh;
        int uf = R + row;
        if (row < 31 && uf < Wout) {
          float u = __expf(-2.f * (Fa[r] + Fb[r]));
          float v = __expf(-(Ga[r] + Gb[r]));
          float fg = (1.f - u) * __builtin_amdgcn_rcpf((1.f + u) * (1.f + v));
          xm[uf * 32 + m] = f2bs(fg);
        }
      }
      asm volatile("s_waitcnt lgkmcnt(0)" ::: "memory");  // wave-local P2->P3

      // ---- phase3: xnext = rbias + R@xmid + cinit (own-tile xm) ----
      const int capX = (R + 30 < Wout - 1) ? (R + 30) : (Wout - 1);
      int rx = R + m; if (rx > capX) rx = capX;
      short8 aX[2];
      afrag2(xm, rx, kh, aX);
      float16 accX;
      const float br = bs[96 + m];
      #pragma unroll
      for (int r = 0; r < 16; r++) accX[r] = br + cinit[r];
      accX = MFMA_B16(aX[0], BW[4][0], accX);
      accX = MFMA_B16(aX[1], BW[4][1], accX);
      #pragma unroll
      for (int r = 0; r < 16; r++) {
        int row = (r & 3) + 8 * (r >> 2) + 4 * kh;
        int uf = R + row;
        if (row < 31 && uf < Wout) xout[uf * 32 + m] = f2bs(accX[r]);
      }
    } else if (newpf) {
      short* dst = bfw[(i + 1) & 1];
      #pragma unroll
      for (int q = 0; q < 7; q++) {
        int c = ptid + q * nP;
        if (c < 896) {
          short8 v;
          #pragma unroll
          for (int j = 0; j < 8; j++) v[j] = f2bs(pfn[q][j]);
          *(short8*)&dst[c * 8] = v;
        }
      }
      for (int t2 = ptid; t2 < 128; t2 += nP) {
        const float* bsrc = (t2 < 32) ? dil_b : (t2 < 64) ? filt_b : (t2 < 96) ? gate_b : res_b;
        bias2[(i + 1) & 1][t2] = bsrc[(i + 1) * 32 + (t2 & 31)];
      }
    }

    if (oldpf) {
      short* dst = bfw[(i + 1) & 1];
      #pragma unroll
      for (int q = 0; q < 4; q++) {
        if (q < nch) {
          short8 v;
          #pragma unroll
          for (int j = 0; j < 8; j++) v[j] = f2bs(pfo[q][j]);
          *(short8*)&dst[(tid + q * NT) * 8] = v;
        }
      }
      if (tid < 128) bias2[(i + 1) & 1][tid] = pbias;
    }
    __syncthreads();                        // single barrier per layer
    Win = Wout;
  }

  // ---- layers 10..15: in-register pipeline on wave 0 ----
  {
    const int t31 = lane & 31;
    const int hb  = lane & 32;
    const int lx32 = lane ^ 32;
    unsigned xcur[8], e32[8], e33[8];
    int mode = 2;
    if (wv == 0) {
      const short* xb0 = xbuf[0];          // L9 wrote xbuf[0]
      int tcl = t31 < Win - 1 ? t31 : Win - 1;
      ldrow(xb0, tcl, kh, xcur);
      ldrow(xb0, 32, kh, e32);
      ldrow(xb0, 33, kh, e33);
      // probe permlane32_swap semantics exactly; fallback to shfl otherwise
      {
        unsigned pa = (unsigned)lane;
        unsigned pb = 64u + (unsigned)lane;
        uv2 pr = __builtin_amdgcn_permlane32_swap(pa, pb, false, false);
        unsigned x0  = (unsigned)__shfl((int)pr[0], 0);
        unsigned x32 = (unsigned)__shfl((int)pr[0], 32);
        unsigned y0  = (unsigned)__shfl((int)pr[1], 0);
        unsigned y32 = (unsigned)__shfl((int)pr[1], 32);
        if      (x0 == 0u  && x32 == 64u && y0 == 32u && y32 == 96u) mode = 0;
        else if (y0 == 0u  && y32 == 64u && x0 == 32u && x32 == 96u) mode = 1;
      }
    }

    #pragma unroll
    for (int i = 10; i < LL; i++) {
      const int d = 1 << (i & 3);
      const int Wout = Win - d - 1;
      // slot map: 10->bfw[0],11->bfw[1],12->bfw[0],13->bfw[1],14->pool,15->bfw[0]
      const short* bw = (i == 14) ? l14w : (i == 15) ? bfw[0] : bfw[i & 1];
      const float* bs = (i == 14) ? l14b : (i == 15) ? bias2[0] : bias2[i & 1];

      if (wv >= 1) {
        const int ptid = tid - 64;
        if (i == 10) {
          float pfA[5][8], pfB[5][8];
          #pragma unroll
          for (int q = 0; q < 5; q++) {
            int c = ptid + q * 192;
            if (c < 896) load_chunk(11, c, pfA[q], dil_w, filt_w, gate_w, res_w);
          }
          #pragma unroll
          for (int q = 0; q < 5; q++) {
            int c = ptid + q * 192;
            if (c < 896) load_chunk(14, c, pfB[q], dil_w, filt_w, gate_w, res_w);
          }
          #pragma unroll
          for (int q = 0; q < 5; q++) {
            int c = ptid + q * 192;
            if (c < 896) {
              short8 vA, vB;
              #pragma unroll
              for (int j = 0; j < 8; j++) { vA[j] = f2bs(pfA[q][j]); vB[j] = f2bs(pfB[q][j]); }
              *(short8*)&bfw[1][c * 8] = vA;
              *(short8*)&l14w[c * 8]   = vB;
            }
          }
          for (int t2 = ptid; t2 < 128; t2 += 192) {
            const float* bsrc = (t2 < 32) ? dil_b : (t2 < 64) ? filt_b : (t2 < 96) ? gate_b : res_b;
            bias2[1][t2] = bsrc[11 * 32 + (t2 & 31)];
            l14b[t2]     = bsrc[14 * 32 + (t2 & 31)];
          }
        } else if (i == 11) {
          stage_layer(12, ptid, bfw[0], bias2[0], dil_w, filt_w, gate_w, res_w,
                      dil_b, filt_b, gate_b, res_b);
        } else if (i == 12) {
          stage_layer(13, ptid, bfw[1], bias2[1], dil_w, filt_w, gate_w, res_w,
                      dil_b, filt_b, gate_b, res_b);
        } else if (i == 13) {
          stage_layer(15, ptid, bfw[0], bias2[0], dil_w, filt_w, gate_w, res_w,
                      dil_b, filt_b, gate_b, res_b);
        }
      }

      if (wv == 0) {
        short8 WA[7][2];
        #pragma unroll
        for (int mt = 0; mt < 7; mt++)
          #pragma unroll
          for (int h = 0; h < 2; h++)
            WA[mt][h] = *(const short8*)&bw[((mt * 2 + h) * 64 + lane) * 8];

        // ---- phase1 (2+2 split: W1.x[t] chain independent of shuffled tap) ----
        unsigned xd[8];
        if (i == 10) {
          int td = t31 + d;                 // d=4: lanes 28..31 -> 32..35
          int ts = td > 31 ? 31 : td;
          #pragma unroll
          for (int q = 0; q < 8; q++) {
            unsigned s = (unsigned)__shfl((int)xcur[q], hb | ts);
            s = (td == 32) ? e32[q] : s;
            s = (td >= 33) ? e33[q] : s;    // clamp Win-1 = 33
            xd[q] = s;
          }
        } else {
          int td = t31 + d; if (td > Win - 1) td = Win - 1;
          int srcd = hb | td;
          #pragma unroll
          for (int q = 0; q < 8; q++) xd[q] = (unsigned)__shfl((int)xcur[q], srcd);
        }
        float16 p1a, p1b;
        #pragma unroll
        for (int g = 0; g < 4; g++) {
          float4 b4 = *(const float4*)&bs[4 * kh + 8 * g];
          p1a[4*g+0] = b4.x; p1a[4*g+1] = b4.y; p1a[4*g+2] = b4.z; p1a[4*g+3] = b4.w;
          p1b[4*g+0] = 0.f;  p1b[4*g+1] = 0.f;  p1b[4*g+2] = 0.f;  p1b[4*g+3] = 0.f;
        }
        p1a = MFMA_B16(WA[1][0], mk8(xcur[0], xcur[1], xcur[2], xcur[3]), p1a);
        p1a = MFMA_B16(WA[1][1], mk8(xcur[4], xcur[5], xcur[6], xcur[7]), p1a);
        p1b = MFMA_B16(WA[0][0], mk8(xd[0], xd[1], xd[2], xd[3]), p1b);
        p1b = MFMA_B16(WA[0][1], mk8(xd[4], xd[5], xd[6], xd[7]), p1b);

        unsigned rb0w[8];
        #pragma unroll
        for (int q = 0; q < 8; q++)
          rb0w[q] = cvtpk(p1a[2 * q] + p1b[2 * q], p1a[2 * q + 1] + p1b[2 * q + 1]);
        exch(rb0w, kh, lx32, mode);
        int t1 = t31 + 1; if (t1 > Wout) t1 = Wout;
        int s1o = hb | t1;
        unsigned rb1w[8];
        #pragma unroll
        for (int q = 0; q < 8; q++) rb1w[q] = (unsigned)__shfl((int)rb0w[q], s1o);

        // ---- phase2 (2+2 splits; rb0 chains independent of shift round) ----
        float16 Fa, Fb, Ga, Gb;
        #pragma unroll
        for (int g = 0; g < 4; g++) {
          float4 bF = *(const float4*)&bs[32 + 4 * kh + 8 * g];
          float4 bG = *(const float4*)&bs[64 + 4 * kh + 8 * g];
          Fa[4*g+0] = bF.x; Fa[4*g+1] = bF.y; Fa[4*g+2] = bF.z; Fa[4*g+3] = bF.w;
          Ga[4*g+0] = bG.x; Ga[4*g+1] = bG.y; Ga[4*g+2] = bG.z; Ga[4*g+3] = bG.w;
          Fb[4*g+0] = 0.f; Fb[4*g+1] = 0.f; Fb[4*g+2] = 0.f; Fb[4*g+3] = 0.f;
          Gb[4*g+0] = 0.f; Gb[4*g+1] = 0.f; Gb[4*g+2] = 0.f; Gb[4*g+3] = 0.f;
        }
        short8 RB00 = mk8(rb0w[0], rb0w[1], rb0w[2], rb0w[3]);
        short8 RB01 = mk8(rb0w[4], rb0w[5], rb0w[6], rb0w[7]);
        short8 RB10 = mk8(rb1w[0], rb1w[1], rb1w[2], rb1w[3]);
        short8 RB11 = mk8(rb1w[4], rb1w[5], rb1w[6], rb1w[7]);
        Fa = MFMA_B16(WA[3][0], RB00, Fa);
        Fa = MFMA_B16(WA[3][1], RB01, Fa);
        Ga = MFMA_B16(WA[5][0], RB00, Ga);
        Ga = MFMA_B16(WA[5][1], RB01, Ga);
        Fb = MFMA_B16(WA[2][0], RB10, Fb);
        Fb = MFMA_B16(WA[2][1], RB11, Fb);
        Gb = MFMA_B16(WA[4][0], RB10, Gb);
        Gb = MFMA_B16(WA[4][1], RB11, Gb);
        float fg[16];
        #pragma unroll
        for (int r = 0; r < 16; r++) {
          float u = __expf(-2.f * (Fa[r] + Fb[r]));
          float v = __expf(-(Ga[r] + Gb[r]));
          fg[r] = (1.f - u) * __builtin_amdgcn_rcpf((1.f + u) * (1.f + v));
        }
        unsigned wxm[8];
        #pragma unroll
        for (int q = 0; q < 8; q++) wxm[q] = cvtpk(fg[2 * q], fg[2 * q + 1]);

        if (i == LL - 1) {
          if (t31 == 0) {
            #pragma unroll
            for (int q = 0; q < 8; q++) {
              int c0 = (2 * q & 3) + 8 * (q >> 1) + 4 * kh;
              *(unsigned*)&xbuf[0][c0] = wxm[q];
            }
          }
        } else {
          // ---- phase3: xnext = rbias + Wr.xm + residual[t+1] ----
          unsigned x1[8];
          #pragma unroll
          for (int q = 0; q < 8; q++) x1[q] = rb1w[q];
          exch(x1, kh, lx32, mode);
          unsigned xmw[8];
          #pragma unroll
          for (int q = 0; q < 8; q++) xmw[q] = wxm[q];
          exch(xmw, kh, lx32, mode);
          float16 accX;
          #pragma unroll
          for (int g = 0; g < 4; g++) {
            float4 bR = *(const float4*)&bs[96 + 4 * kh + 8 * g];
            #pragma unroll
            for (int j = 0; j < 4; j++) {
              int r = 4 * g + j;
              unsigned w = x1[r >> 1];
              float rv = (r & 1) ? u2f(w & 0xFFFF0000u) : u2f(w << 16);
              accX[r] = ((const float*)&bR)[j] + rv;
            }
          }
          accX = MFMA_B16(WA[6][0], mk8(xmw[0], xmw[1], xmw[2], xmw[3]), accX);
          accX = MFMA_B16(WA[6][1], mk8(xmw[4], xmw[5], xmw[6], xmw[7]), accX);
          #pragma unroll
          for (int q = 0; q < 8; q++) xcur[q] = cvtpk(accX[2 * q], accX[2 * q + 1]);
          exch(xcur, kh, lx32, mode);
        }
      }
      if (i <= 13) __syncthreads();
      Win = Wout;
    }
  }
  __syncthreads();   // xbuf[0] spill handoff to all waves

  // ---- tail: skip (K=32, original) then 6 coalesced split-K stages ----
  {
    const short* xmt = xbuf[0];
    float acc = skip_b[15 * 256 + tid];
    const float* wr = skip_w + (15 * 256 + tid) * 32;
    #pragma unroll
    for (int k = 0; k < 32; k += 4) {
      float4 w = *(const float4*)&wr[k];
      acc += (w.x * b2f(xmt[k]) + w.y * b2f(xmt[k+1])) + (w.z * b2f(xmt[k+2]) + w.w * b2f(xmt[k+3]));
    }
    vecA[tid] = fmaxf(acc, 0.f);
  }
  __syncthreads();
  mv_stage<256, 256, true >(end1_w, end1_b, vecA, vecB, tid);
  __syncthreads();
  mv_stage<256, 256, false>(end2_w, end2_b, vecB, vecA, tid);
  __syncthreads();
  mv_stage<128, 256, true >(fc1_w, fc1_b, vecA, vecB, tid);
  __syncthreads();
  mv_stage<128, 128, true >(fc2_w, fc2_b, vecB, vecA, tid);
  __syncthreads();
  mv_stage< 64, 128, true >(fc3_w, fc3_b, vecA, vecB, tid);
  __syncthreads();
  mv_stage<256,  64, false>(fc4_w, fc4_b, vecB, out + b * 256, tid);
}

extern "C" void kernel_launch(void* const* d_in, const int* in_sizes, int n_in,
                              void* d_out, int out_size, void* d_ws, size_t ws_size,
                              hipStream_t stream) {
  wavenet_kernel<<<BB, NT, 0, stream>>>(
      (const int*)d_in[0],    (const float*)d_in[1],  (const float*)d_in[2],  (const float*)d_in[3],
      (const float*)d_in[4],  (const float*)d_in[5],  (const float*)d_in[6],  (const float*)d_in[7],
      (const float*)d_in[8],  (const float*)d_in[9],  (const float*)d_in[10], (const float*)d_in[11],
      (const float*)d_in[12], (const float*)d_in[13], (const float*)d_in[14], (const float*)d_in[15],
      (const float*)d_in[16], (const float*)d_in[17], (const float*)d_in[18], (const float*)d_in[19],
      (const float*)d_in[20], (const float*)d_in[21], (const float*)d_in[22], (const float*)d_in[23],
      (const float*)d_in[24], (const float*)d_in[25], (float*)d_out);
}